// Round 4
// baseline (681.717 us; speedup 1.0000x reference)
//
#include <hip/hip_runtime.h>
#include <hip/hip_bf16.h>

#define BN_  16
#define CH   1024
#define MIDC 512
#define NPIX 2304   // 48*48

typedef __bf16 bf16x8 __attribute__((ext_vector_type(8)));
typedef __bf16 bf16x4 __attribute__((ext_vector_type(4)));
typedef float  f32x4  __attribute__((ext_vector_type(4)));

typedef __attribute__((address_space(1))) void void_g;
typedef __attribute__((address_space(3))) void void_l;

__device__ __forceinline__ void gll16(const void* g, void* l) {
  __builtin_amdgcn_global_load_lds((const void_g*)g, (void_l*)l, 16, 0, 0);
}

// ---------------------------------------------------------------------------
// 256x256 8-wave 8-phase double-buffered BT GEMM (HK-style schedule, plain HIP)
// C[m][n] = sum_k A[m][k]*B[n][k]; A,B row-major bf16 [*,K]; M,N %256==0, K %64==0.
// 512 thr = 8 waves (2M x 4N), per-wave out 128x64 (8x4 frags 16x16, f32x4 acc).
// BK=64; LDS = 2buf x (A 256x64 + B 256x64) bf16 = 128 KiB.
// Swizzle (T2): 8-elem chunk at slot s of row r holds logical chunk s^(r&7);
// staged via pre-swizzled GLOBAL source (gll16 LDS dest linear, rule #21).
// Schedule (T3+T4): per K-tile 4 phases; phase p = {12 ds_read_b128 for C-octant
// (mh=p>>1, nh=p&1) | stage half-tile p of tile t+1 -> s_barrier -> setprio(1)
// 16 MFMA setprio(0) -> s_barrier}; vmcnt(0) ONLY at p==3 (counted, never mid-tile).
// Grid XCD-swizzled (all launches nwg%8==0).
// EPI: 0 none(bf16) 1 col scale/shift+relu(bf16) 2 row bias(bf16)
//      3 scalar scale(bf16) 4 row bias + residual, f32 out
// ---------------------------------------------------------------------------
template<int EPI>
__global__ __launch_bounds__(512)
void gemm256(const __hip_bfloat16* __restrict__ Ag, int lda, long sA,
             const __hip_bfloat16* __restrict__ Bg, int ldb, long sB,
             void* __restrict__ Cg, int ldc, long sC,
             int K,
             const float* __restrict__ e0, const float* __restrict__ e1,
             const float* __restrict__ resid, long sR, float fscale)
{
  __shared__ __align__(16) __hip_bfloat16 lds[65536];   // [A 2x16384 | B 2x16384]
  const int tid = threadIdx.x;
  const int l   = tid & 63;
  const int w   = tid >> 6;

  // XCD-aware bijective remap (nwg % 8 == 0 for every launch below)
  const int gx = gridDim.x, gy = gridDim.y;
  const int nwg = gx * gy * gridDim.z;
  const int L  = blockIdx.x + gx * (blockIdx.y + gy * blockIdx.z);
  const int wg = (L & 7) * (nwg >> 3) + (L >> 3);
  const int pb = gx * gy;
  const int bz = wg / pb;
  const int rem = wg - bz * pb;
  const int m0 = (rem % gx) * 256;
  const int n0 = (rem / gx) * 256;

  // Staging geometry: per half-tile (128 rows x 64 cols) 2 gll16/thread.
  // call c, wave w, lane l -> LDS elem half*8192 + c*4096 + w*512 + l*8
  //   row = half*128 + c*64 + w*8 + (l>>3), slot = l&7; row&7 == (l>>3)&7.
  const int srow = w * 8 + (l >> 3);               // 0..63
  const int schk = (l & 7) ^ (l >> 3);             // pre-swizzled source chunk
  const __hip_bfloat16* Ab = Ag + (long)bz * sA + (long)(m0 + srow) * lda + schk * 8;
  const __hip_bfloat16* Bb = Bg + (long)bz * sB + (long)(n0 + srow) * ldb + schk * 8;
  const int stg = w * 512;                         // wave-uniform LDS base (elems)

  auto stageA = [&](int buf, int half, long kofs) {
    __hip_bfloat16* d = lds + buf * 16384 + half * 8192 + stg;
    gll16(Ab + kofs + (long)(half * 128) * lda,      d);
    gll16(Ab + kofs + (long)(half * 128 + 64) * lda, d + 4096);
  };
  auto stageB = [&](int buf, int half, long kofs) {
    __hip_bfloat16* d = lds + 32768 + buf * 16384 + half * 8192 + stg;
    gll16(Bb + kofs + (long)(half * 128) * ldb,      d);
    gll16(Bb + kofs + (long)(half * 128 + 64) * ldb, d + 4096);
  };

  const int wr = w >> 2, wc = w & 3;               // wave grid 2x4
  const int fr = l & 15;
  const int fc = l >> 4;
  const int slot0 = ((fc)     ^ (fr & 7)) * 8;     // kk=0 chunk slot (elems)
  const int slot1 = ((4 + fc) ^ (fr & 7)) * 8;     // kk=1

  f32x4 acc[8][4] = {};

  // prologue: stage K-tile 0 into buf 0
  stageA(0, 0, 0); stageA(0, 1, 0); stageB(0, 0, 0); stageB(0, 1, 0);
  asm volatile("s_waitcnt vmcnt(0)" ::: "memory");
  __builtin_amdgcn_s_barrier();

  const int NT = K >> 6;
  for (int t = 0; t < NT; ++t) {
    const __hip_bfloat16* lAc = lds + (t & 1) * 16384;
    const __hip_bfloat16* lBc = lds + 32768 + (t & 1) * 16384;
    const int  nb   = (t & 1) ^ 1;
    const long knxt = (long)(t + 1) * 64;
    const bool more = (t + 1 < NT);
#pragma unroll
    for (int p = 0; p < 4; ++p) {
      const int mh = p >> 1, nh = p & 1;
      bf16x8 avA[4][2], avB[2][2];
#pragma unroll
      for (int i = 0; i < 4; ++i) {
        const int row = wr * 128 + (mh * 4 + i) * 16 + fr;
        avA[i][0] = *(const bf16x8*)(lAc + row * 64 + slot0);
        avA[i][1] = *(const bf16x8*)(lAc + row * 64 + slot1);
      }
#pragma unroll
      for (int j = 0; j < 2; ++j) {
        const int row = wc * 64 + (nh * 2 + j) * 16 + fr;
        avB[j][0] = *(const bf16x8*)(lBc + row * 64 + slot0);
        avB[j][1] = *(const bf16x8*)(lBc + row * 64 + slot1);
      }
      if (more) {
        if (p < 2) stageA(nb, p, knxt); else stageB(nb, p - 2, knxt);
      }
      __builtin_amdgcn_s_barrier();
      __builtin_amdgcn_s_setprio(1);
#pragma unroll
      for (int i = 0; i < 4; ++i)
#pragma unroll
        for (int j = 0; j < 2; ++j) {
          acc[mh * 4 + i][nh * 2 + j] = __builtin_amdgcn_mfma_f32_16x16x32_bf16(
              avA[i][0], avB[j][0], acc[mh * 4 + i][nh * 2 + j], 0, 0, 0);
          acc[mh * 4 + i][nh * 2 + j] = __builtin_amdgcn_mfma_f32_16x16x32_bf16(
              avA[i][1], avB[j][1], acc[mh * 4 + i][nh * 2 + j], 0, 0, 0);
        }
      __builtin_amdgcn_s_setprio(0);
      if (p == 3) asm volatile("s_waitcnt vmcnt(0)" ::: "memory");
      __builtin_amdgcn_s_barrier();
    }
  }

  // C/D layout: col = lane&15, row = (lane>>4)*4 + reg
  const int rb0 = m0 + wr * 128 + (l >> 4) * 4;
  const int cb0 = n0 + wc * 64 + fr;
  if constexpr (EPI == 4) {
    float* Cb = (float*)Cg + (long)bz * sC;
    const float* Rb = resid + (long)bz * sR;
#pragma unroll
    for (int mi = 0; mi < 8; ++mi) {
#pragma unroll
      for (int r = 0; r < 4; ++r) {
        const int row = rb0 + mi * 16 + r;
        const float bias = e0[row];
#pragma unroll
        for (int ni = 0; ni < 4; ++ni) {
          const long idx = (long)row * ldc + cb0 + ni * 16;
          Cb[idx] = acc[mi][ni][r] + bias + Rb[idx];
        }
      }
    }
  } else {
    __hip_bfloat16* Cb = (__hip_bfloat16*)Cg + (long)bz * sC;
#pragma unroll
    for (int mi = 0; mi < 8; ++mi) {
#pragma unroll
      for (int r = 0; r < 4; ++r) {
        const int row = rb0 + mi * 16 + r;
#pragma unroll
        for (int ni = 0; ni < 4; ++ni) {
          const int col = cb0 + ni * 16;
          float v = acc[mi][ni][r];
          if constexpr (EPI == 1) { v = fmaxf(v * e0[col] + e1[col], 0.f); }
          if constexpr (EPI == 2) { v += e0[row]; }
          if constexpr (EPI == 3) { v *= fscale; }
          Cb[(long)row * ldc + col] = __float2bfloat16(v);
        }
      }
    }
  }
}

// ---------------------------------------------------------------------------
// Row softmax in-place on bf16 logits, one 256-thread block per row of 2304.
// ---------------------------------------------------------------------------
__global__ __launch_bounds__(256)
void softmax_rows(__hip_bfloat16* __restrict__ z)
{
  const long row = blockIdx.x;
  __hip_bfloat16* p = z + row * NPIX;
  const int t = threadIdx.x;
  const int lane = t & 63, wave = t >> 6;

  float v[9];
  bf16x8 pk = *(const bf16x8*)(p + t * 8);
#pragma unroll
  for (int i = 0; i < 8; ++i) v[i] = (float)pk[i];
  v[8] = __bfloat162float(p[2048 + t]);

  float mx = v[0];
#pragma unroll
  for (int i = 1; i < 9; ++i) mx = fmaxf(mx, v[i]);
#pragma unroll
  for (int o = 32; o > 0; o >>= 1) mx = fmaxf(mx, __shfl_xor(mx, o));
  __shared__ float redm[4], reds[4];
  if (lane == 0) redm[wave] = mx;
  __syncthreads();
  mx = fmaxf(fmaxf(redm[0], redm[1]), fmaxf(redm[2], redm[3]));

  float s = 0.f;
#pragma unroll
  for (int i = 0; i < 9; ++i) { v[i] = __expf(v[i] - mx); s += v[i]; }
#pragma unroll
  for (int o = 32; o > 0; o >>= 1) s += __shfl_xor(s, o);
  if (lane == 0) reds[wave] = s;
  __syncthreads();
  s = reds[0] + reds[1] + reds[2] + reds[3];
  const float inv = 1.f / s;

  bf16x8 ok;
#pragma unroll
  for (int i = 0; i < 8; ++i) ok[i] = (__bf16)(v[i] * inv);
  *(bf16x8*)(p + t * 8) = ok;
  p[2048 + t] = __float2bfloat16(v[8] * inv);
}

// ---------------------------------------------------------------------------
// x[b][c][n] f32  ->  xt[b][n][c] bf16   (64x64 LDS tile transpose)
// ---------------------------------------------------------------------------
__global__ __launch_bounds__(256)
void transpose_cvt(const float* __restrict__ x, __hip_bfloat16* __restrict__ xt)
{
  __shared__ float tile[64 * 65];
  const int n0 = blockIdx.x * 64, c0 = blockIdx.y * 64;
  const long bo = (long)blockIdx.z * CH * NPIX;
  const int t = threadIdx.x;
#pragma unroll
  for (int i = 0; i < 16; ++i) {
    const int idx = i * 256 + t;
    const int cl = idx >> 6, nl = idx & 63;
    tile[cl * 65 + nl] = x[bo + (long)(c0 + cl) * NPIX + n0 + nl];
  }
  __syncthreads();
#pragma unroll
  for (int i = 0; i < 16; ++i) {
    const int idx = i * 256 + t;
    const int nl = idx >> 6, cl = idx & 63;
    xt[bo + (long)(n0 + nl) * CH + c0 + cl] = __float2bfloat16(tile[cl * 65 + nl]);
  }
}

// All four weights are 512*1024 = 524288 elems; one launch, float4 -> bf16x4.
__global__ __launch_bounds__(256)
void cvt4(const float* __restrict__ a, const float* __restrict__ b,
          const float* __restrict__ c, const float* __restrict__ d,
          __hip_bfloat16* oa, __hip_bfloat16* ob,
          __hip_bfloat16* oc, __hip_bfloat16* od)
{
  const int i = (blockIdx.x * 256 + threadIdx.x) * 4;
  const float* s; __hip_bfloat16* o;
  switch (blockIdx.y) {
    case 0:  s = a; o = oa; break;
    case 1:  s = b; o = ob; break;
    case 2:  s = c; o = oc; break;
    default: s = d; o = od; break;
  }
  const float4 v = *(const float4*)(s + i);
  bf16x4 wv;
  wv[0] = (__bf16)v.x; wv[1] = (__bf16)v.y; wv[2] = (__bf16)v.z; wv[3] = (__bf16)v.w;
  *(bf16x4*)(o + i) = wv;
}

// Fold conv-bias + BN into per-channel scale/shift:  out = relu(acc*sc + sh)
__global__ void prep_scales(const float* bf_, const float* gf, const float* bef,
                            const float* mf, const float* vf,
                            const float* bg_, const float* gg, const float* beg,
                            const float* mg, const float* vg,
                            float* sc, float* sh)
{
  const int r = blockIdx.x * 256 + threadIdx.x;
  if (r >= 1024) return;
  int j; const float *b, *g, *be, *m, *vv;
  if (r < 512) { b = bf_; g = gf; be = bef; m = mf; vv = vf; j = r; }
  else         { b = bg_; g = gg; be = beg; m = mg; vv = vg; j = r - 512; }
  const float inv = g[j] / sqrtf(vv[j] + 1e-5f);
  sc[r] = inv;
  sh[r] = (b[j] - m[j]) * inv + be[j];
}

extern "C" void kernel_launch(void* const* d_in, const int* in_sizes, int n_in,
                              void* d_out, int out_size, void* d_ws, size_t ws_size,
                              hipStream_t stream)
{
  const float* x     = (const float*)d_in[0];
  const float* Wf    = (const float*)d_in[1];
  const float* bf_   = (const float*)d_in[2];
  const float* gf    = (const float*)d_in[3];
  const float* betaf = (const float*)d_in[4];
  const float* mf    = (const float*)d_in[5];
  const float* vf    = (const float*)d_in[6];
  const float* Wg    = (const float*)d_in[7];
  const float* bg_   = (const float*)d_in[8];
  const float* gg    = (const float*)d_in[9];
  const float* betag = (const float*)d_in[10];
  const float* mg    = (const float*)d_in[11];
  const float* vg    = (const float*)d_in[12];
  const float* Wh    = (const float*)d_in[13];
  const float* bh    = (const float*)d_in[14];
  const float* Wv    = (const float*)d_in[15];
  const float* bv    = (const float*)d_in[16];
  float* out = (float*)d_out;
  (void)in_sizes; (void)n_in; (void)out_size; (void)ws_size;

  char* ws = (char*)d_ws;
  size_t off = 0;
  auto take = [&](size_t bytes) -> char* {
    char* p = ws + off;
    off += (bytes + 255) & ~(size_t)255;
    return p;
  };
  __hip_bfloat16* xt   = (__hip_bfloat16*)take((size_t)BN_ * NPIX * CH * 2);    // 75.5 MB
  __hip_bfloat16* fgT  = (__hip_bfloat16*)take((size_t)BN_ * NPIX * 1024 * 2);  // 75.5 MB
  __hip_bfloat16* hbuf = (__hip_bfloat16*)take((size_t)BN_ * MIDC * NPIX * 2);  // 37.7 MB
  __hip_bfloat16* om   = (__hip_bfloat16*)take((size_t)BN_ * NPIX * MIDC * 2);  // 37.7 MB
  __hip_bfloat16* zat  = (__hip_bfloat16*)take((size_t)BN_ * NPIX * NPIX * 2);  // 169.9 MB
  __hip_bfloat16* Wfgb = (__hip_bfloat16*)take((size_t)1024 * CH * 2);
  __hip_bfloat16* Whb  = (__hip_bfloat16*)take((size_t)MIDC * CH * 2);
  __hip_bfloat16* Wvb  = (__hip_bfloat16*)take((size_t)CH * MIDC * 2);
  float* scfg = (float*)take(1024 * 4);
  float* shfg = (float*)take(1024 * 4);

  prep_scales<<<dim3(4), dim3(256), 0, stream>>>(bf_, gf, betaf, mf, vf,
                                                 bg_, gg, betag, mg, vg, scfg, shfg);
  cvt4<<<dim3(512, 4), dim3(256), 0, stream>>>(Wf, Wg, Wh, Wv,
                                               Wfgb, Wfgb + 512 * 1024, Whb, Wvb);
  transpose_cvt<<<dim3(36, 16, BN_), dim3(256), 0, stream>>>(x, xt);

  // fgT[b][n][r] = sum_c xt[b][n][c] * Wfg[r][c]   (+ fused BN+ReLU per col r)
  gemm256<1><<<dim3(9, 4, BN_), dim3(512), 0, stream>>>(
      xt, CH, (long)NPIX * CH, Wfgb, CH, 0L,
      fgT, 1024, (long)NPIX * 1024, CH,
      scfg, shfg, nullptr, 0L, 0.f);

  // h[b][m][n] = sum_c Wh[m][c] * xt[b][n][c]  (+ bias per row m)
  gemm256<2><<<dim3(2, 9, BN_), dim3(512), 0, stream>>>(
      Whb, CH, 0L, xt, CH, (long)NPIX * CH,
      hbuf, NPIX, (long)MIDC * NPIX, CH,
      bh, nullptr, nullptr, 0L, 0.f);

  // z[b][i][j] = (sum_m fT[i][m] * gT[j][m]) * 512^-0.5   -> bf16 logits
  gemm256<3><<<dim3(9, 9, BN_), dim3(512), 0, stream>>>(
      fgT, 1024, (long)NPIX * 1024, fgT + 512, 1024, (long)NPIX * 1024,
      zat, NPIX, (long)NPIX * NPIX, MIDC,
      nullptr, nullptr, nullptr, 0L, 0.044194173824159216f);

  softmax_rows<<<dim3(BN_ * NPIX), dim3(256), 0, stream>>>(zat);

  // om[b][i][o] = sum_j attn[i][j] * h[o][j]
  gemm256<0><<<dim3(9, 2, BN_), dim3(512), 0, stream>>>(
      zat, NPIX, (long)NPIX * NPIX, hbuf, NPIX, (long)MIDC * NPIX,
      om, MIDC, (long)NPIX * MIDC, NPIX,
      nullptr, nullptr, nullptr, 0L, 0.f);

  // out[b][c][n] = sum_o Wv[c][o] * om[b][n][o] + bv[c] + x[b][c][n]
  gemm256<4><<<dim3(4, 9, BN_), dim3(512), 0, stream>>>(
      Wvb, MIDC, 0L, om, MIDC, (long)NPIX * MIDC,
      out, NPIX, (long)CH * NPIX, MIDC,
      bv, nullptr, x, (long)CH * NPIX, 0.f);
}

// Round 5
// 609.183 us; speedup vs baseline: 1.1191x; 1.1191x over previous
//
#include <hip/hip_runtime.h>
#include <hip/hip_bf16.h>

#define BN_  16
#define CH   1024
#define MIDC 512
#define NPIX 2304   // 48*48

typedef __bf16 bf16x8 __attribute__((ext_vector_type(8)));
typedef __bf16 bf16x4 __attribute__((ext_vector_type(4)));
typedef float  f32x4  __attribute__((ext_vector_type(4)));

typedef __attribute__((address_space(1))) void void_g;
typedef __attribute__((address_space(3))) void void_l;

__device__ __forceinline__ void gll16(const void* g, void* l) {
  __builtin_amdgcn_global_load_lds((const void_g*)g, (void_l*)l, 16, 0, 0);
}

// ---------------------------------------------------------------------------
// 128x128 BT GEMM (r2-measured: PV 142us, 0 bank conflicts, ~5 blocks/CU).
// C[m][n] = sum_k A[m][k]*B[n][k]; BK=64; 256 thr, 2x2 waves, 64x64/wave.
// Chunk-XOR swizzle via pre-swizzled global source; XCD-swizzled grid.
// EPI: 0 none 1 col scale/shift+relu 2 row bias 3 scalar scale 4 row bias+resid f32
// ---------------------------------------------------------------------------
template<int EPI>
__global__ __launch_bounds__(256)
void gemm_bt(const __hip_bfloat16* __restrict__ Ag, int lda, long sA,
             const __hip_bfloat16* __restrict__ Bg, int ldb, long sB,
             void* __restrict__ Cg, int ldc, long sC,
             int K,
             const float* __restrict__ e0, const float* __restrict__ e1,
             const float* __restrict__ resid, long sR, float fscale)
{
  __shared__ __align__(16) __hip_bfloat16 lA[128 * 64];
  __shared__ __align__(16) __hip_bfloat16 lB[128 * 64];
  const int tid  = threadIdx.x;
  const int lane = tid & 63;
  const int wave = tid >> 6;

  const int gx = gridDim.x, gy = gridDim.y;
  const int nwg = gx * gy * gridDim.z;
  const int L  = blockIdx.x + gx * (blockIdx.y + gy * blockIdx.z);
  const int wg = (L & 7) * (nwg >> 3) + (L >> 3);
  const int pb = gx * gy;
  const int bz = wg / pb;
  const int rem = wg - bz * pb;
  const int m0 = (rem % gx) * 128;
  const int n0 = (rem / gx) * 128;

  const int srow = tid >> 3;                     // 0..31 (+32 per call)
  const int schk = (tid & 7) ^ (srow & 7);       // pre-swizzled source chunk
  const __hip_bfloat16* Ab = Ag + (long)bz * sA + (long)(m0 + srow) * lda + schk * 8;
  const __hip_bfloat16* Bb = Bg + (long)bz * sB + (long)(n0 + srow) * ldb + schk * 8;
  __hip_bfloat16* lAw = lA + wave * 512;
  __hip_bfloat16* lBw = lB + wave * 512;

  const int wr = wave >> 1, wc = wave & 1;
  const int fr = lane & 15;
  const int fc = lane >> 4;

  f32x4 acc[4][4] = {};

  for (int k0 = 0; k0 < K; k0 += 64) {
#pragma unroll
    for (int c = 0; c < 4; ++c) {
      gll16(Ab + k0 + (long)c * 32 * lda, lAw + c * 2048);
      gll16(Bb + k0 + (long)c * 32 * ldb, lBw + c * 2048);
    }
    __syncthreads();
#pragma unroll
    for (int kk = 0; kk < 2; ++kk) {
      bf16x8 af[4], bfv[4];
#pragma unroll
      for (int i = 0; i < 4; ++i) {
        const int ra = wr * 64 + i * 16 + fr;
        af[i]  = *(const bf16x8*)(lA + ra * 64 + (((kk * 4 + fc) ^ (fr & 7)) * 8));
        const int rb = wc * 64 + i * 16 + fr;
        bfv[i] = *(const bf16x8*)(lB + rb * 64 + (((kk * 4 + fc) ^ (fr & 7)) * 8));
      }
#pragma unroll
      for (int mi = 0; mi < 4; ++mi)
#pragma unroll
        for (int ni = 0; ni < 4; ++ni)
          acc[mi][ni] = __builtin_amdgcn_mfma_f32_16x16x32_bf16(af[mi], bfv[ni], acc[mi][ni], 0, 0, 0);
    }
    __syncthreads();
  }

  const int rbase = m0 + wr * 64 + (lane >> 4) * 4;
  const int cbase = n0 + wc * 64 + fr;
  if constexpr (EPI == 4) {
    float* Cb = (float*)Cg + (long)bz * sC;
    const float* Rb = resid + (long)bz * sR;
#pragma unroll
    for (int mi = 0; mi < 4; ++mi) {
#pragma unroll
      for (int r = 0; r < 4; ++r) {
        const int row = rbase + mi * 16 + r;
        const float bias = e0[row];
#pragma unroll
        for (int ni = 0; ni < 4; ++ni) {
          const long idx = (long)row * ldc + cbase + ni * 16;
          Cb[idx] = acc[mi][ni][r] + bias + Rb[idx];
        }
      }
    }
  } else {
    __hip_bfloat16* Cb = (__hip_bfloat16*)Cg + (long)bz * sC;
#pragma unroll
    for (int mi = 0; mi < 4; ++mi) {
#pragma unroll
      for (int r = 0; r < 4; ++r) {
        const int row = rbase + mi * 16 + r;
#pragma unroll
        for (int ni = 0; ni < 4; ++ni) {
          const int col = cbase + ni * 16;
          float v = acc[mi][ni][r];
          if constexpr (EPI == 1) { v = fmaxf(v * e0[col] + e1[col], 0.f); }
          if constexpr (EPI == 2) { v += e0[row]; }
          if constexpr (EPI == 3) { v *= fscale; }
          Cb[(long)row * ldc + col] = __float2bfloat16(v);
        }
      }
    }
  }
}

// ---------------------------------------------------------------------------
// 256x256 8-wave 8-phase double-buffered BT GEMM (for LARGE grids only: z).
// ---------------------------------------------------------------------------
template<int EPI>
__global__ __launch_bounds__(512)
void gemm256(const __hip_bfloat16* __restrict__ Ag, int lda, long sA,
             const __hip_bfloat16* __restrict__ Bg, int ldb, long sB,
             void* __restrict__ Cg, int ldc, long sC,
             int K,
             const float* __restrict__ e0, const float* __restrict__ e1,
             const float* __restrict__ resid, long sR, float fscale)
{
  __shared__ __align__(16) __hip_bfloat16 lds[65536];   // [A 2x16384 | B 2x16384]
  const int tid = threadIdx.x;
  const int l   = tid & 63;
  const int w   = tid >> 6;

  const int gx = gridDim.x, gy = gridDim.y;
  const int nwg = gx * gy * gridDim.z;
  const int L  = blockIdx.x + gx * (blockIdx.y + gy * blockIdx.z);
  const int wg = (L & 7) * (nwg >> 3) + (L >> 3);
  const int pb = gx * gy;
  const int bz = wg / pb;
  const int rem = wg - bz * pb;
  const int m0 = (rem % gx) * 256;
  const int n0 = (rem / gx) * 256;

  const int srow = w * 8 + (l >> 3);               // 0..63
  const int schk = (l & 7) ^ (l >> 3);             // pre-swizzled source chunk
  const __hip_bfloat16* Ab = Ag + (long)bz * sA + (long)(m0 + srow) * lda + schk * 8;
  const __hip_bfloat16* Bb = Bg + (long)bz * sB + (long)(n0 + srow) * ldb + schk * 8;
  const int stg = w * 512;

  auto stageA = [&](int buf, int half, long kofs) {
    __hip_bfloat16* d = lds + buf * 16384 + half * 8192 + stg;
    gll16(Ab + kofs + (long)(half * 128) * lda,      d);
    gll16(Ab + kofs + (long)(half * 128 + 64) * lda, d + 4096);
  };
  auto stageB = [&](int buf, int half, long kofs) {
    __hip_bfloat16* d = lds + 32768 + buf * 16384 + half * 8192 + stg;
    gll16(Bb + kofs + (long)(half * 128) * ldb,      d);
    gll16(Bb + kofs + (long)(half * 128 + 64) * ldb, d + 4096);
  };

  const int wr = w >> 2, wc = w & 3;               // wave grid 2x4
  const int fr = l & 15;
  const int fc = l >> 4;
  const int slot0 = ((fc)     ^ (fr & 7)) * 8;
  const int slot1 = ((4 + fc) ^ (fr & 7)) * 8;

  f32x4 acc[8][4] = {};

  stageA(0, 0, 0); stageA(0, 1, 0); stageB(0, 0, 0); stageB(0, 1, 0);
  asm volatile("s_waitcnt vmcnt(0)" ::: "memory");
  __builtin_amdgcn_s_barrier();

  const int NT = K >> 6;
  for (int t = 0; t < NT; ++t) {
    const __hip_bfloat16* lAc = lds + (t & 1) * 16384;
    const __hip_bfloat16* lBc = lds + 32768 + (t & 1) * 16384;
    const int  nb   = (t & 1) ^ 1;
    const long knxt = (long)(t + 1) * 64;
    const bool more = (t + 1 < NT);
#pragma unroll
    for (int p = 0; p < 4; ++p) {
      const int mh = p >> 1, nh = p & 1;
      bf16x8 avA[4][2], avB[2][2];
#pragma unroll
      for (int i = 0; i < 4; ++i) {
        const int row = wr * 128 + (mh * 4 + i) * 16 + fr;
        avA[i][0] = *(const bf16x8*)(lAc + row * 64 + slot0);
        avA[i][1] = *(const bf16x8*)(lAc + row * 64 + slot1);
      }
#pragma unroll
      for (int j = 0; j < 2; ++j) {
        const int row = wc * 64 + (nh * 2 + j) * 16 + fr;
        avB[j][0] = *(const bf16x8*)(lBc + row * 64 + slot0);
        avB[j][1] = *(const bf16x8*)(lBc + row * 64 + slot1);
      }
      if (more) {
        if (p < 2) stageA(nb, p, knxt); else stageB(nb, p - 2, knxt);
      }
      __builtin_amdgcn_s_barrier();
      __builtin_amdgcn_s_setprio(1);
#pragma unroll
      for (int i = 0; i < 4; ++i)
#pragma unroll
        for (int j = 0; j < 2; ++j) {
          acc[mh * 4 + i][nh * 2 + j] = __builtin_amdgcn_mfma_f32_16x16x32_bf16(
              avA[i][0], avB[j][0], acc[mh * 4 + i][nh * 2 + j], 0, 0, 0);
          acc[mh * 4 + i][nh * 2 + j] = __builtin_amdgcn_mfma_f32_16x16x32_bf16(
              avA[i][1], avB[j][1], acc[mh * 4 + i][nh * 2 + j], 0, 0, 0);
        }
      __builtin_amdgcn_s_setprio(0);
      if (p == 3) asm volatile("s_waitcnt vmcnt(0)" ::: "memory");
      __builtin_amdgcn_s_barrier();
    }
  }

  const int rb0 = m0 + wr * 128 + (l >> 4) * 4;
  const int cb0 = n0 + wc * 64 + fr;
  {
    __hip_bfloat16* Cb = (__hip_bfloat16*)Cg + (long)bz * sC;
#pragma unroll
    for (int mi = 0; mi < 8; ++mi) {
#pragma unroll
      for (int r = 0; r < 4; ++r) {
        const int row = rb0 + mi * 16 + r;
#pragma unroll
        for (int ni = 0; ni < 4; ++ni) {
          const int col = cb0 + ni * 16;
          float v = acc[mi][ni][r];
          if constexpr (EPI == 1) { v = fmaxf(v * e0[col] + e1[col], 0.f); }
          if constexpr (EPI == 2) { v += e0[row]; }
          if constexpr (EPI == 3) { v *= fscale; }
          Cb[(long)row * ldc + col] = __float2bfloat16(v);
        }
      }
    }
  }
}

// ---------------------------------------------------------------------------
// Row softmax in-place on bf16 logits, one 256-thread block per row of 2304.
// ---------------------------------------------------------------------------
__global__ __launch_bounds__(256)
void softmax_rows(__hip_bfloat16* __restrict__ z)
{
  const long row = blockIdx.x;
  __hip_bfloat16* p = z + row * NPIX;
  const int t = threadIdx.x;
  const int lane = t & 63, wave = t >> 6;

  float v[9];
  bf16x8 pk = *(const bf16x8*)(p + t * 8);
#pragma unroll
  for (int i = 0; i < 8; ++i) v[i] = (float)pk[i];
  v[8] = __bfloat162float(p[2048 + t]);

  float mx = v[0];
#pragma unroll
  for (int i = 1; i < 9; ++i) mx = fmaxf(mx, v[i]);
#pragma unroll
  for (int o = 32; o > 0; o >>= 1) mx = fmaxf(mx, __shfl_xor(mx, o));
  __shared__ float redm[4], reds[4];
  if (lane == 0) redm[wave] = mx;
  __syncthreads();
  mx = fmaxf(fmaxf(redm[0], redm[1]), fmaxf(redm[2], redm[3]));

  float s = 0.f;
#pragma unroll
  for (int i = 0; i < 9; ++i) { v[i] = __expf(v[i] - mx); s += v[i]; }
#pragma unroll
  for (int o = 32; o > 0; o >>= 1) s += __shfl_xor(s, o);
  if (lane == 0) reds[wave] = s;
  __syncthreads();
  s = reds[0] + reds[1] + reds[2] + reds[3];
  const float inv = 1.f / s;

  bf16x8 ok;
#pragma unroll
  for (int i = 0; i < 8; ++i) ok[i] = (__bf16)(v[i] * inv);
  *(bf16x8*)(p + t * 8) = ok;
  p[2048 + t] = __float2bfloat16(v[8] * inv);
}

// ---------------------------------------------------------------------------
// x[b][c][n] f32  ->  xt[b][n][c] bf16   (64x64 LDS tile transpose)
// ---------------------------------------------------------------------------
__global__ __launch_bounds__(256)
void transpose_cvt(const float* __restrict__ x, __hip_bfloat16* __restrict__ xt)
{
  __shared__ float tile[64 * 65];
  const int n0 = blockIdx.x * 64, c0 = blockIdx.y * 64;
  const long bo = (long)blockIdx.z * CH * NPIX;
  const int t = threadIdx.x;
#pragma unroll
  for (int i = 0; i < 16; ++i) {
    const int idx = i * 256 + t;
    const int cl = idx >> 6, nl = idx & 63;
    tile[cl * 65 + nl] = x[bo + (long)(c0 + cl) * NPIX + n0 + nl];
  }
  __syncthreads();
#pragma unroll
  for (int i = 0; i < 16; ++i) {
    const int idx = i * 256 + t;
    const int nl = idx >> 6, cl = idx & 63;
    xt[bo + (long)(n0 + nl) * CH + c0 + cl] = __float2bfloat16(tile[cl * 65 + nl]);
  }
}

// All four weights are 512*1024 = 524288 elems; one launch, float4 -> bf16x4.
__global__ __launch_bounds__(256)
void cvt4(const float* __restrict__ a, const float* __restrict__ b,
          const float* __restrict__ c, const float* __restrict__ d,
          __hip_bfloat16* oa, __hip_bfloat16* ob,
          __hip_bfloat16* oc, __hip_bfloat16* od)
{
  const int i = (blockIdx.x * 256 + threadIdx.x) * 4;
  const float* s; __hip_bfloat16* o;
  switch (blockIdx.y) {
    case 0:  s = a; o = oa; break;
    case 1:  s = b; o = ob; break;
    case 2:  s = c; o = oc; break;
    default: s = d; o = od; break;
  }
  const float4 v = *(const float4*)(s + i);
  bf16x4 wv;
  wv[0] = (__bf16)v.x; wv[1] = (__bf16)v.y; wv[2] = (__bf16)v.z; wv[3] = (__bf16)v.w;
  *(bf16x4*)(o + i) = wv;
}

// Fold conv-bias + BN into per-channel scale/shift:  out = relu(acc*sc + sh)
__global__ void prep_scales(const float* bf_, const float* gf, const float* bef,
                            const float* mf, const float* vf,
                            const float* bg_, const float* gg, const float* beg,
                            const float* mg, const float* vg,
                            float* sc, float* sh)
{
  const int r = blockIdx.x * 256 + threadIdx.x;
  if (r >= 1024) return;
  int j; const float *b, *g, *be, *m, *vv;
  if (r < 512) { b = bf_; g = gf; be = bef; m = mf; vv = vf; j = r; }
  else         { b = bg_; g = gg; be = beg; m = mg; vv = vg; j = r - 512; }
  const float inv = g[j] / sqrtf(vv[j] + 1e-5f);
  sc[r] = inv;
  sh[r] = (b[j] - m[j]) * inv + be[j];
}

extern "C" void kernel_launch(void* const* d_in, const int* in_sizes, int n_in,
                              void* d_out, int out_size, void* d_ws, size_t ws_size,
                              hipStream_t stream)
{
  const float* x     = (const float*)d_in[0];
  const float* Wf    = (const float*)d_in[1];
  const float* bf_   = (const float*)d_in[2];
  const float* gf    = (const float*)d_in[3];
  const float* betaf = (const float*)d_in[4];
  const float* mf    = (const float*)d_in[5];
  const float* vf    = (const float*)d_in[6];
  const float* Wg    = (const float*)d_in[7];
  const float* bg_   = (const float*)d_in[8];
  const float* gg    = (const float*)d_in[9];
  const float* betag = (const float*)d_in[10];
  const float* mg    = (const float*)d_in[11];
  const float* vg    = (const float*)d_in[12];
  const float* Wh    = (const float*)d_in[13];
  const float* bh    = (const float*)d_in[14];
  const float* Wv    = (const float*)d_in[15];
  const float* bv    = (const float*)d_in[16];
  float* out = (float*)d_out;
  (void)in_sizes; (void)n_in; (void)out_size; (void)ws_size;

  char* ws = (char*)d_ws;
  size_t off = 0;
  auto take = [&](size_t bytes) -> char* {
    char* p = ws + off;
    off += (bytes + 255) & ~(size_t)255;
    return p;
  };
  __hip_bfloat16* xt   = (__hip_bfloat16*)take((size_t)BN_ * NPIX * CH * 2);    // 75.5 MB
  __hip_bfloat16* fgT  = (__hip_bfloat16*)take((size_t)BN_ * NPIX * 1024 * 2);  // 75.5 MB
  __hip_bfloat16* hbuf = (__hip_bfloat16*)take((size_t)BN_ * MIDC * NPIX * 2);  // 37.7 MB
  __hip_bfloat16* om   = (__hip_bfloat16*)take((size_t)BN_ * NPIX * MIDC * 2);  // 37.7 MB
  __hip_bfloat16* zat  = (__hip_bfloat16*)take((size_t)BN_ * NPIX * NPIX * 2);  // 169.9 MB
  __hip_bfloat16* Wfgb = (__hip_bfloat16*)take((size_t)1024 * CH * 2);
  __hip_bfloat16* Whb  = (__hip_bfloat16*)take((size_t)MIDC * CH * 2);
  __hip_bfloat16* Wvb  = (__hip_bfloat16*)take((size_t)CH * MIDC * 2);
  float* scfg = (float*)take(1024 * 4);
  float* shfg = (float*)take(1024 * 4);

  prep_scales<<<dim3(4), dim3(256), 0, stream>>>(bf_, gf, betaf, mf, vf,
                                                 bg_, gg, betag, mg, vg, scfg, shfg);
  cvt4<<<dim3(512, 4), dim3(256), 0, stream>>>(Wf, Wg, Wh, Wv,
                                               Wfgb, Wfgb + 512 * 1024, Whb, Wvb);
  transpose_cvt<<<dim3(36, 16, BN_), dim3(256), 0, stream>>>(x, xt);

  // fgT[b][n][r] = sum_c xt[b][n][c] * Wfg[r][c]   (+ fused BN+ReLU per col r)
  gemm_bt<1><<<dim3(18, 8, BN_), dim3(256), 0, stream>>>(
      xt, CH, (long)NPIX * CH, Wfgb, CH, 0L,
      fgT, 1024, (long)NPIX * 1024, CH,
      scfg, shfg, nullptr, 0L, 0.f);

  // h[b][m][n] = sum_c Wh[m][c] * xt[b][n][c]  (+ bias per row m)
  gemm_bt<2><<<dim3(4, 18, BN_), dim3(256), 0, stream>>>(
      Whb, CH, 0L, xt, CH, (long)NPIX * CH,
      hbuf, NPIX, (long)MIDC * NPIX, CH,
      bh, nullptr, nullptr, 0L, 0.f);

  // z[b][i][j] = (sum_m fT[i][m] * gT[j][m]) * 512^-0.5   -> bf16 logits
  // Large grid (1296 blocks) -> 8-phase 256^2 kernel.
  gemm256<3><<<dim3(9, 9, BN_), dim3(512), 0, stream>>>(
      fgT, 1024, (long)NPIX * 1024, fgT + 512, 1024, (long)NPIX * 1024,
      zat, NPIX, (long)NPIX * NPIX, MIDC,
      nullptr, nullptr, nullptr, 0L, 0.044194173824159216f);

  softmax_rows<<<dim3(BN_ * NPIX), dim3(256), 0, stream>>>(zat);

  // om[b][i][o] = sum_j attn[i][j] * h[o][j]
  gemm_bt<0><<<dim3(18, 4, BN_), dim3(256), 0, stream>>>(
      zat, NPIX, (long)NPIX * NPIX, hbuf, NPIX, (long)MIDC * NPIX,
      om, MIDC, (long)NPIX * MIDC, NPIX,
      nullptr, nullptr, nullptr, 0L, 0.f);

  // out[b][c][n] = sum_o Wv[c][o] * om[b][n][o] + bv[c] + x[b][c][n]
  gemm_bt<4><<<dim3(8, 18, BN_), dim3(256), 0, stream>>>(
      Wvb, MIDC, 0L, om, MIDC, (long)NPIX * MIDC,
      out, NPIX, (long)CH * NPIX, MIDC,
      bv, nullptr, x, (long)CH * NPIX, 0.f);
}

// Round 6
// 606.760 us; speedup vs baseline: 1.1235x; 1.0040x over previous
//
#include <hip/hip_runtime.h>
#include <hip/hip_bf16.h>

#define BN_  16
#define CH   1024
#define MIDC 512
#define NPIX 2304   // 48*48
#define NCHK 36     // NPIX/64 column chunks per attn row

typedef __bf16 bf16x8 __attribute__((ext_vector_type(8)));
typedef __bf16 bf16x4 __attribute__((ext_vector_type(4)));
typedef float  f32x4  __attribute__((ext_vector_type(4)));

typedef __attribute__((address_space(1))) void void_g;
typedef __attribute__((address_space(3))) void void_l;

__device__ __forceinline__ void gll16(const void* g, void* l) {
  __builtin_amdgcn_global_load_lds((const void_g*)g, (void_l*)l, 16, 0, 0);
}

// ---------------------------------------------------------------------------
// 128x128 BT GEMM (r2-measured: 0 bank conflicts, ~5 blocks/CU).
// C[m][n] = sum_k A[m][k]*B[n][k]; BK=64; 256 thr, 2x2 waves, 64x64/wave.
// Chunk-XOR swizzle via pre-swizzled global source; XCD-swizzled grid.
// EPI: 0 none(bf16)
//      1 per-col scale/shift + relu (bf16)
//      2 per-row bias (bf16)
//      4 per-row bias + residual, f32 out
//      5 per-row scale from e0[bz*NPIX+row] (bf16)              [PV: x invS]
//      6 E=exp2(acc*fscale) bf16 + per-(row,64chunk) partial sums -> pw
// ---------------------------------------------------------------------------
template<int EPI>
__global__ __launch_bounds__(256)
void gemm_bt(const __hip_bfloat16* __restrict__ Ag, int lda, long sA,
             const __hip_bfloat16* __restrict__ Bg, int ldb, long sB,
             void* __restrict__ Cg, int ldc, long sC,
             int K,
             const float* __restrict__ e0, const float* __restrict__ e1,
             const float* __restrict__ resid, long sR, float fscale,
             float* __restrict__ pw)
{
  __shared__ __align__(16) __hip_bfloat16 lA[128 * 64];
  __shared__ __align__(16) __hip_bfloat16 lB[128 * 64];
  const int tid  = threadIdx.x;
  const int lane = tid & 63;
  const int wave = tid >> 6;

  const int gx = gridDim.x, gy = gridDim.y;
  const int nwg = gx * gy * gridDim.z;
  const int L  = blockIdx.x + gx * (blockIdx.y + gy * blockIdx.z);
  const int wg = (L & 7) * (nwg >> 3) + (L >> 3);
  const int pb = gx * gy;
  const int bz = wg / pb;
  const int rem = wg - bz * pb;
  const int m0 = (rem % gx) * 128;
  const int n0 = (rem / gx) * 128;

  const int srow = tid >> 3;                     // 0..31 (+32 per call)
  const int schk = (tid & 7) ^ (srow & 7);       // pre-swizzled source chunk
  const __hip_bfloat16* Ab = Ag + (long)bz * sA + (long)(m0 + srow) * lda + schk * 8;
  const __hip_bfloat16* Bb = Bg + (long)bz * sB + (long)(n0 + srow) * ldb + schk * 8;
  __hip_bfloat16* lAw = lA + wave * 512;
  __hip_bfloat16* lBw = lB + wave * 512;

  const int wr = wave >> 1, wc = wave & 1;
  const int fr = lane & 15;
  const int fc = lane >> 4;

  f32x4 acc[4][4] = {};

  for (int k0 = 0; k0 < K; k0 += 64) {
#pragma unroll
    for (int c = 0; c < 4; ++c) {
      gll16(Ab + k0 + (long)c * 32 * lda, lAw + c * 2048);
      gll16(Bb + k0 + (long)c * 32 * ldb, lBw + c * 2048);
    }
    __syncthreads();
#pragma unroll
    for (int kk = 0; kk < 2; ++kk) {
      bf16x8 af[4], bfv[4];
#pragma unroll
      for (int i = 0; i < 4; ++i) {
        const int ra = wr * 64 + i * 16 + fr;
        af[i]  = *(const bf16x8*)(lA + ra * 64 + (((kk * 4 + fc) ^ (fr & 7)) * 8));
        const int rb = wc * 64 + i * 16 + fr;
        bfv[i] = *(const bf16x8*)(lB + rb * 64 + (((kk * 4 + fc) ^ (fr & 7)) * 8));
      }
#pragma unroll
      for (int mi = 0; mi < 4; ++mi)
#pragma unroll
        for (int ni = 0; ni < 4; ++ni)
          acc[mi][ni] = __builtin_amdgcn_mfma_f32_16x16x32_bf16(af[mi], bfv[ni], acc[mi][ni], 0, 0, 0);
    }
    __syncthreads();
  }

  // C/D layout: col = lane&15, row = (lane>>4)*4 + reg
  const int rbase = m0 + wr * 64 + (lane >> 4) * 4;
  const int cbase = n0 + wc * 64 + fr;
  if constexpr (EPI == 4) {
    float* Cb = (float*)Cg + (long)bz * sC;
    const float* Rb = resid + (long)bz * sR;
#pragma unroll
    for (int mi = 0; mi < 4; ++mi) {
#pragma unroll
      for (int r = 0; r < 4; ++r) {
        const int row = rbase + mi * 16 + r;
        const float bias = e0[row];
#pragma unroll
        for (int ni = 0; ni < 4; ++ni) {
          const long idx = (long)row * ldc + cbase + ni * 16;
          Cb[idx] = acc[mi][ni][r] + bias + Rb[idx];
        }
      }
    }
  } else if constexpr (EPI == 6) {
    // E = exp2(z*fscale) (z >= 0 since f,g >= 0 -> no max subtraction needed;
    // zs <= ~25 so E well within bf16 range). Partial row sums per 64-col
    // wave chunk -> pw[b][chunk][row] (coalesced for the reduce kernel).
    __hip_bfloat16* Cb = (__hip_bfloat16*)Cg + (long)bz * sC;
    float* pp = pw + ((long)bz * NCHK + (n0 >> 6) + wc) * NPIX;
#pragma unroll
    for (int mi = 0; mi < 4; ++mi) {
#pragma unroll
      for (int r = 0; r < 4; ++r) {
        const int row = rbase + mi * 16 + r;
        float rs = 0.f;
#pragma unroll
        for (int ni = 0; ni < 4; ++ni) {
          const int col = cbase + ni * 16;
          const float ev = exp2f(acc[mi][ni][r] * fscale);
          rs += ev;
          Cb[(long)row * ldc + col] = __float2bfloat16(ev);
        }
#pragma unroll
        for (int o = 1; o < 16; o <<= 1) rs += __shfl_xor(rs, o);
        if (fr == 0) pp[row] = rs;
      }
    }
  } else {
    __hip_bfloat16* Cb = (__hip_bfloat16*)Cg + (long)bz * sC;
#pragma unroll
    for (int mi = 0; mi < 4; ++mi) {
#pragma unroll
      for (int r = 0; r < 4; ++r) {
        const int row = rbase + mi * 16 + r;
        float rsc = 0.f;
        if constexpr (EPI == 5) { rsc = e0[(long)bz * NPIX + row]; }
#pragma unroll
        for (int ni = 0; ni < 4; ++ni) {
          const int col = cbase + ni * 16;
          float v = acc[mi][ni][r];
          if constexpr (EPI == 1) { v = fmaxf(v * e0[col] + e1[col], 0.f); }
          if constexpr (EPI == 2) { v += e0[row]; }
          if constexpr (EPI == 5) { v *= rsc; }
          Cb[(long)row * ldc + col] = __float2bfloat16(v);
        }
      }
    }
  }
}

// ---------------------------------------------------------------------------
// invS[b][row] = 1 / sum_c partials[b][c][row]   (grid (NPIX/256, BN_))
// ---------------------------------------------------------------------------
__global__ __launch_bounds__(256)
void reduce_invs(const float* __restrict__ pp, float* __restrict__ invS)
{
  const int row = blockIdx.x * 256 + threadIdx.x;
  const int b   = blockIdx.y;
  const float* p = pp + (long)b * NCHK * NPIX;
  float s = 0.f;
#pragma unroll
  for (int c = 0; c < NCHK; ++c) s += p[(long)c * NPIX + row];
  invS[(long)b * NPIX + row] = 1.f / s;
}

// ---------------------------------------------------------------------------
// x[b][c][n] f32  ->  xt[b][n][c] bf16   (64x64 LDS tile transpose)
// ---------------------------------------------------------------------------
__global__ __launch_bounds__(256)
void transpose_cvt(const float* __restrict__ x, __hip_bfloat16* __restrict__ xt)
{
  __shared__ float tile[64 * 65];
  const int n0 = blockIdx.x * 64, c0 = blockIdx.y * 64;
  const long bo = (long)blockIdx.z * CH * NPIX;
  const int t = threadIdx.x;
#pragma unroll
  for (int i = 0; i < 16; ++i) {
    const int idx = i * 256 + t;
    const int cl = idx >> 6, nl = idx & 63;
    tile[cl * 65 + nl] = x[bo + (long)(c0 + cl) * NPIX + n0 + nl];
  }
  __syncthreads();
#pragma unroll
  for (int i = 0; i < 16; ++i) {
    const int idx = i * 256 + t;
    const int nl = idx >> 6, cl = idx & 63;
    xt[bo + (long)(n0 + nl) * CH + c0 + cl] = __float2bfloat16(tile[cl * 65 + nl]);
  }
}

// All four weights are 512*1024 = 524288 elems; one launch, float4 -> bf16x4.
__global__ __launch_bounds__(256)
void cvt4(const float* __restrict__ a, const float* __restrict__ b,
          const float* __restrict__ c, const float* __restrict__ d,
          __hip_bfloat16* oa, __hip_bfloat16* ob,
          __hip_bfloat16* oc, __hip_bfloat16* od)
{
  const int i = (blockIdx.x * 256 + threadIdx.x) * 4;
  const float* s; __hip_bfloat16* o;
  switch (blockIdx.y) {
    case 0:  s = a; o = oa; break;
    case 1:  s = b; o = ob; break;
    case 2:  s = c; o = oc; break;
    default: s = d; o = od; break;
  }
  const float4 v = *(const float4*)(s + i);
  bf16x4 wv;
  wv[0] = (__bf16)v.x; wv[1] = (__bf16)v.y; wv[2] = (__bf16)v.z; wv[3] = (__bf16)v.w;
  *(bf16x4*)(o + i) = wv;
}

// Fold conv-bias + BN into per-channel scale/shift:  out = relu(acc*sc + sh)
__global__ void prep_scales(const float* bf_, const float* gf, const float* bef,
                            const float* mf, const float* vf,
                            const float* bg_, const float* gg, const float* beg,
                            const float* mg, const float* vg,
                            float* sc, float* sh)
{
  const int r = blockIdx.x * 256 + threadIdx.x;
  if (r >= 1024) return;
  int j; const float *b, *g, *be, *m, *vv;
  if (r < 512) { b = bf_; g = gf; be = bef; m = mf; vv = vf; j = r; }
  else         { b = bg_; g = gg; be = beg; m = mg; vv = vg; j = r - 512; }
  const float inv = g[j] / sqrtf(vv[j] + 1e-5f);
  sc[r] = inv;
  sh[r] = (b[j] - m[j]) * inv + be[j];
}

extern "C" void kernel_launch(void* const* d_in, const int* in_sizes, int n_in,
                              void* d_out, int out_size, void* d_ws, size_t ws_size,
                              hipStream_t stream)
{
  const float* x     = (const float*)d_in[0];
  const float* Wf    = (const float*)d_in[1];
  const float* bf_   = (const float*)d_in[2];
  const float* gf    = (const float*)d_in[3];
  const float* betaf = (const float*)d_in[4];
  const float* mf    = (const float*)d_in[5];
  const float* vf    = (const float*)d_in[6];
  const float* Wg    = (const float*)d_in[7];
  const float* bg_   = (const float*)d_in[8];
  const float* gg    = (const float*)d_in[9];
  const float* betag = (const float*)d_in[10];
  const float* mg    = (const float*)d_in[11];
  const float* vg    = (const float*)d_in[12];
  const float* Wh    = (const float*)d_in[13];
  const float* bh    = (const float*)d_in[14];
  const float* Wv    = (const float*)d_in[15];
  const float* bv    = (const float*)d_in[16];
  float* out = (float*)d_out;
  (void)in_sizes; (void)n_in; (void)out_size; (void)ws_size;

  char* ws = (char*)d_ws;
  size_t off = 0;
  auto take = [&](size_t bytes) -> char* {
    char* p = ws + off;
    off += (bytes + 255) & ~(size_t)255;
    return p;
  };
  __hip_bfloat16* xt   = (__hip_bfloat16*)take((size_t)BN_ * NPIX * CH * 2);    // 75.5 MB
  __hip_bfloat16* fgT  = (__hip_bfloat16*)take((size_t)BN_ * NPIX * 1024 * 2);  // 75.5 MB
  __hip_bfloat16* hbuf = (__hip_bfloat16*)take((size_t)BN_ * MIDC * NPIX * 2);  // 37.7 MB
  __hip_bfloat16* om   = (__hip_bfloat16*)take((size_t)BN_ * NPIX * MIDC * 2);  // 37.7 MB
  __hip_bfloat16* zat  = (__hip_bfloat16*)take((size_t)BN_ * NPIX * NPIX * 2);  // 169.9 MB
  __hip_bfloat16* Wfgb = (__hip_bfloat16*)take((size_t)1024 * CH * 2);
  __hip_bfloat16* Whb  = (__hip_bfloat16*)take((size_t)MIDC * CH * 2);
  __hip_bfloat16* Wvb  = (__hip_bfloat16*)take((size_t)CH * MIDC * 2);
  float* scfg = (float*)take(1024 * 4);
  float* shfg = (float*)take(1024 * 4);
  float* partials = (float*)take((size_t)BN_ * NCHK * NPIX * 4);               // 5.3 MB
  float* invS     = (float*)take((size_t)BN_ * NPIX * 4);

  prep_scales<<<dim3(4), dim3(256), 0, stream>>>(bf_, gf, betaf, mf, vf,
                                                 bg_, gg, betag, mg, vg, scfg, shfg);
  cvt4<<<dim3(512, 4), dim3(256), 0, stream>>>(Wf, Wg, Wh, Wv,
                                               Wfgb, Wfgb + 512 * 1024, Whb, Wvb);
  transpose_cvt<<<dim3(36, 16, BN_), dim3(256), 0, stream>>>(x, xt);

  // fgT[b][n][r] = sum_c xt[b][n][c] * Wfg[r][c]   (+ fused BN+ReLU per col r)
  gemm_bt<1><<<dim3(18, 8, BN_), dim3(256), 0, stream>>>(
      xt, CH, (long)NPIX * CH, Wfgb, CH, 0L,
      fgT, 1024, (long)NPIX * 1024, CH,
      scfg, shfg, nullptr, 0L, 0.f, nullptr);

  // h[b][m][n] = sum_c Wh[m][c] * xt[b][n][c]  (+ bias per row m)
  gemm_bt<2><<<dim3(4, 18, BN_), dim3(256), 0, stream>>>(
      Whb, CH, 0L, xt, CH, (long)NPIX * CH,
      hbuf, NPIX, (long)MIDC * NPIX, CH,
      bh, nullptr, nullptr, 0L, 0.f, nullptr);

  // E[b][i][j] = exp(z*scale); partial row sums -> partials  (softmax fused)
  const float sc_log2e = (float)(0.044194173824159216 * 1.4426950408889634);
  gemm_bt<6><<<dim3(18, 18, BN_), dim3(256), 0, stream>>>(
      fgT, 1024, (long)NPIX * 1024, fgT + 512, 1024, (long)NPIX * 1024,
      zat, NPIX, (long)NPIX * NPIX, MIDC,
      nullptr, nullptr, nullptr, 0L, sc_log2e, partials);

  reduce_invs<<<dim3(NPIX / 256, BN_), dim3(256), 0, stream>>>(partials, invS);

  // om[b][i][o] = invS[i] * sum_j E[i][j] * h[o][j]
  gemm_bt<5><<<dim3(18, 4, BN_), dim3(256), 0, stream>>>(
      zat, NPIX, (long)NPIX * NPIX, hbuf, NPIX, (long)MIDC * NPIX,
      om, MIDC, (long)NPIX * MIDC, NPIX,
      invS, nullptr, nullptr, 0L, 0.f, nullptr);

  // out[b][c][n] = sum_o Wv[c][o] * om[b][n][o] + bv[c] + x[b][c][n]
  gemm_bt<4><<<dim3(8, 18, BN_), dim3(256), 0, stream>>>(
      Wvb, MIDC, 0L, om, MIDC, (long)NPIX * MIDC,
      out, NPIX, (long)CH * NPIX, MIDC,
      bv, nullptr, x, (long)CH * NPIX, 0.f, nullptr);
}

// Round 7
// 566.762 us; speedup vs baseline: 1.2028x; 1.0706x over previous
//
#include <hip/hip_runtime.h>
#include <hip/hip_bf16.h>

#define BN_  16
#define CH   1024
#define MIDC 512
#define NPIX 2304   // 48*48
#define NCHK 36     // NPIX/64 column chunks per attn row

typedef __bf16 bf16x8 __attribute__((ext_vector_type(8)));
typedef __bf16 bf16x4 __attribute__((ext_vector_type(4)));
typedef float  f32x4  __attribute__((ext_vector_type(4)));

typedef __attribute__((address_space(1))) void void_g;
typedef __attribute__((address_space(3))) void void_l;

__device__ __forceinline__ void gll16(const void* g, void* l) {
  __builtin_amdgcn_global_load_lds((const void_g*)g, (void_l*)l, 16, 0, 0);
}

// ---------------------------------------------------------------------------
// 128x128 BT GEMM (r2-measured: 0 bank conflicts, ~5 blocks/CU).
// C[m][n] = sum_k A[m][k]*B[n][k]; BK=64; 256 thr, 2x2 waves, 64x64/wave.
// Chunk-XOR swizzle via pre-swizzled global source; XCD-swizzled grid.
// EPI: 0 none(bf16)
//      1 per-col scale/shift + relu (bf16)
//      2 per-row bias (bf16)
//      4 acc*invS[col] + per-row bias + residual, f32 out      [final conv]
//      6 E=exp2(acc*fscale) bf16 + per-(row,64chunk) partial sums -> pw
// ---------------------------------------------------------------------------
template<int EPI>
__global__ __launch_bounds__(256)
void gemm_bt(const __hip_bfloat16* __restrict__ Ag, int lda, long sA,
             const __hip_bfloat16* __restrict__ Bg, int ldb, long sB,
             void* __restrict__ Cg, int ldc, long sC,
             int K,
             const float* __restrict__ e0, const float* __restrict__ e1,
             const float* __restrict__ resid, long sR, float fscale,
             float* __restrict__ pw)
{
  __shared__ __align__(16) __hip_bfloat16 lA[128 * 64];
  __shared__ __align__(16) __hip_bfloat16 lB[128 * 64];
  const int tid  = threadIdx.x;
  const int lane = tid & 63;
  const int wave = tid >> 6;

  const int gx = gridDim.x, gy = gridDim.y;
  const int nwg = gx * gy * gridDim.z;
  const int L  = blockIdx.x + gx * (blockIdx.y + gy * blockIdx.z);
  const int wg = (L & 7) * (nwg >> 3) + (L >> 3);
  const int pb = gx * gy;
  const int bz = wg / pb;
  const int rem = wg - bz * pb;
  const int m0 = (rem % gx) * 128;
  const int n0 = (rem / gx) * 128;

  const int srow = tid >> 3;                     // 0..31 (+32 per call)
  const int schk = (tid & 7) ^ (srow & 7);       // pre-swizzled source chunk
  const __hip_bfloat16* Ab = Ag + (long)bz * sA + (long)(m0 + srow) * lda + schk * 8;
  const __hip_bfloat16* Bb = Bg + (long)bz * sB + (long)(n0 + srow) * ldb + schk * 8;
  __hip_bfloat16* lAw = lA + wave * 512;
  __hip_bfloat16* lBw = lB + wave * 512;

  const int wr = wave >> 1, wc = wave & 1;
  const int fr = lane & 15;
  const int fc = lane >> 4;

  f32x4 acc[4][4] = {};

  for (int k0 = 0; k0 < K; k0 += 64) {
#pragma unroll
    for (int c = 0; c < 4; ++c) {
      gll16(Ab + k0 + (long)c * 32 * lda, lAw + c * 2048);
      gll16(Bb + k0 + (long)c * 32 * ldb, lBw + c * 2048);
    }
    __syncthreads();
#pragma unroll
    for (int kk = 0; kk < 2; ++kk) {
      bf16x8 af[4], bfv[4];
#pragma unroll
      for (int i = 0; i < 4; ++i) {
        const int ra = wr * 64 + i * 16 + fr;
        af[i]  = *(const bf16x8*)(lA + ra * 64 + (((kk * 4 + fc) ^ (fr & 7)) * 8));
        const int rb = wc * 64 + i * 16 + fr;
        bfv[i] = *(const bf16x8*)(lB + rb * 64 + (((kk * 4 + fc) ^ (fr & 7)) * 8));
      }
#pragma unroll
      for (int mi = 0; mi < 4; ++mi)
#pragma unroll
        for (int ni = 0; ni < 4; ++ni)
          acc[mi][ni] = __builtin_amdgcn_mfma_f32_16x16x32_bf16(af[mi], bfv[ni], acc[mi][ni], 0, 0, 0);
    }
    __syncthreads();
  }

  // C/D layout: col = lane&15, row = (lane>>4)*4 + reg
  const int rbase = m0 + wr * 64 + (lane >> 4) * 4;
  const int cbase = n0 + wc * 64 + fr;
  if constexpr (EPI == 4) {
    float* Cb = (float*)Cg + (long)bz * sC;
    const float* Rb = resid + (long)bz * sR;
    float ivc[4];
#pragma unroll
    for (int ni = 0; ni < 4; ++ni) ivc[ni] = e1[(long)bz * NPIX + cbase + ni * 16];
#pragma unroll
    for (int mi = 0; mi < 4; ++mi) {
#pragma unroll
      for (int r = 0; r < 4; ++r) {
        const int row = rbase + mi * 16 + r;
        const float bias = e0[row];
#pragma unroll
        for (int ni = 0; ni < 4; ++ni) {
          const long idx = (long)row * ldc + cbase + ni * 16;
          Cb[idx] = acc[mi][ni][r] * ivc[ni] + bias + Rb[idx];
        }
      }
    }
  } else if constexpr (EPI == 6) {
    // E = exp2(z*fscale) (z >= 0 since f,g >= 0 -> no max subtraction needed).
    // Partial row sums per 64-col wave chunk -> pw[b][chunk][row].
    __hip_bfloat16* Cb = (__hip_bfloat16*)Cg + (long)bz * sC;
    float* pp = pw + ((long)bz * NCHK + (n0 >> 6) + wc) * NPIX;
#pragma unroll
    for (int mi = 0; mi < 4; ++mi) {
#pragma unroll
      for (int r = 0; r < 4; ++r) {
        const int row = rbase + mi * 16 + r;
        float rs = 0.f;
#pragma unroll
        for (int ni = 0; ni < 4; ++ni) {
          const int col = cbase + ni * 16;
          const float ev = exp2f(acc[mi][ni][r] * fscale);
          rs += ev;
          Cb[(long)row * ldc + col] = __float2bfloat16(ev);
        }
#pragma unroll
        for (int o = 1; o < 16; o <<= 1) rs += __shfl_xor(rs, o);
        if (fr == 0) pp[row] = rs;
      }
    }
  } else {
    __hip_bfloat16* Cb = (__hip_bfloat16*)Cg + (long)bz * sC;
#pragma unroll
    for (int mi = 0; mi < 4; ++mi) {
#pragma unroll
      for (int r = 0; r < 4; ++r) {
        const int row = rbase + mi * 16 + r;
#pragma unroll
        for (int ni = 0; ni < 4; ++ni) {
          const int col = cbase + ni * 16;
          float v = acc[mi][ni][r];
          if constexpr (EPI == 1) { v = fmaxf(v * e0[col] + e1[col], 0.f); }
          if constexpr (EPI == 2) { v += e0[row]; }
          Cb[(long)row * ldc + col] = __float2bfloat16(v);
        }
      }
    }
  }
}

// ---------------------------------------------------------------------------
// invS[b][row] = 1 / sum_c partials[b][c][row]   (grid (NPIX/256, BN_))
// ---------------------------------------------------------------------------
__global__ __launch_bounds__(256)
void reduce_invs(const float* __restrict__ pp, float* __restrict__ invS)
{
  const int row = blockIdx.x * 256 + threadIdx.x;
  const int b   = blockIdx.y;
  const float* p = pp + (long)b * NCHK * NPIX;
  float s = 0.f;
#pragma unroll
  for (int c = 0; c < NCHK; ++c) s += p[(long)c * NPIX + row];
  invS[(long)b * NPIX + row] = 1.f / s;
}

// ---------------------------------------------------------------------------
// x[b][c][n] f32  ->  xt[b][n][c] bf16   (64x64 LDS tile transpose)
// ---------------------------------------------------------------------------
__global__ __launch_bounds__(256)
void transpose_cvt(const float* __restrict__ x, __hip_bfloat16* __restrict__ xt)
{
  __shared__ float tile[64 * 65];
  const int n0 = blockIdx.x * 64, c0 = blockIdx.y * 64;
  const long bo = (long)blockIdx.z * CH * NPIX;
  const int t = threadIdx.x;
#pragma unroll
  for (int i = 0; i < 16; ++i) {
    const int idx = i * 256 + t;
    const int cl = idx >> 6, nl = idx & 63;
    tile[cl * 65 + nl] = x[bo + (long)(c0 + cl) * NPIX + n0 + nl];
  }
  __syncthreads();
#pragma unroll
  for (int i = 0; i < 16; ++i) {
    const int idx = i * 256 + t;
    const int nl = idx >> 6, cl = idx & 63;
    xt[bo + (long)(n0 + nl) * CH + c0 + cl] = __float2bfloat16(tile[cl * 65 + nl]);
  }
}

// All four weights are 512*1024 = 524288 elems; one launch, float4 -> bf16x4.
__global__ __launch_bounds__(256)
void cvt4(const float* __restrict__ a, const float* __restrict__ b,
          const float* __restrict__ c, const float* __restrict__ d,
          __hip_bfloat16* oa, __hip_bfloat16* ob,
          __hip_bfloat16* oc, __hip_bfloat16* od)
{
  const int i = (blockIdx.x * 256 + threadIdx.x) * 4;
  const float* s; __hip_bfloat16* o;
  switch (blockIdx.y) {
    case 0:  s = a; o = oa; break;
    case 1:  s = b; o = ob; break;
    case 2:  s = c; o = oc; break;
    default: s = d; o = od; break;
  }
  const float4 v = *(const float4*)(s + i);
  bf16x4 wv;
  wv[0] = (__bf16)v.x; wv[1] = (__bf16)v.y; wv[2] = (__bf16)v.z; wv[3] = (__bf16)v.w;
  *(bf16x4*)(o + i) = wv;
}

// Fold conv-bias + BN into per-channel scale/shift:  out = relu(acc*sc + sh)
__global__ void prep_scales(const float* bf_, const float* gf, const float* bef,
                            const float* mf, const float* vf,
                            const float* bg_, const float* gg, const float* beg,
                            const float* mg, const float* vg,
                            float* sc, float* sh)
{
  const int r = blockIdx.x * 256 + threadIdx.x;
  if (r >= 1024) return;
  int j; const float *b, *g, *be, *m, *vv;
  if (r < 512) { b = bf_; g = gf; be = bef; m = mf; vv = vf; j = r; }
  else         { b = bg_; g = gg; be = beg; m = mg; vv = vg; j = r - 512; }
  const float inv = g[j] / sqrtf(vv[j] + 1e-5f);
  sc[r] = inv;
  sh[r] = (b[j] - m[j]) * inv + be[j];
}

extern "C" void kernel_launch(void* const* d_in, const int* in_sizes, int n_in,
                              void* d_out, int out_size, void* d_ws, size_t ws_size,
                              hipStream_t stream)
{
  const float* x     = (const float*)d_in[0];
  const float* Wf    = (const float*)d_in[1];
  const float* bf_   = (const float*)d_in[2];
  const float* gf    = (const float*)d_in[3];
  const float* betaf = (const float*)d_in[4];
  const float* mf    = (const float*)d_in[5];
  const float* vf    = (const float*)d_in[6];
  const float* Wg    = (const float*)d_in[7];
  const float* bg_   = (const float*)d_in[8];
  const float* gg    = (const float*)d_in[9];
  const float* betag = (const float*)d_in[10];
  const float* mg    = (const float*)d_in[11];
  const float* vg    = (const float*)d_in[12];
  const float* Wh    = (const float*)d_in[13];
  const float* bh    = (const float*)d_in[14];
  const float* Wv    = (const float*)d_in[15];
  const float* bv    = (const float*)d_in[16];
  float* out = (float*)d_out;
  (void)in_sizes; (void)n_in; (void)out_size; (void)ws_size;

  char* ws = (char*)d_ws;
  size_t off = 0;
  auto take = [&](size_t bytes) -> char* {
    char* p = ws + off;
    off += (bytes + 255) & ~(size_t)255;
    return p;
  };
  __hip_bfloat16* xt   = (__hip_bfloat16*)take((size_t)BN_ * NPIX * CH * 2);    // 75.5 MB
  __hip_bfloat16* fgT  = (__hip_bfloat16*)take((size_t)BN_ * NPIX * 1024 * 2);  // 75.5 MB
  __hip_bfloat16* hbuf = (__hip_bfloat16*)take((size_t)BN_ * MIDC * NPIX * 2);  // 37.7 MB
  __hip_bfloat16* om   = (__hip_bfloat16*)take((size_t)BN_ * NPIX * MIDC * 2);  // 37.7 MB
  __hip_bfloat16* zat  = (__hip_bfloat16*)take((size_t)BN_ * NPIX * NPIX * 2);  // 169.9 MB
  __hip_bfloat16* Wfgb = (__hip_bfloat16*)take((size_t)1024 * CH * 2);
  __hip_bfloat16* Whb  = (__hip_bfloat16*)take((size_t)MIDC * CH * 2);
  __hip_bfloat16* Wvb  = (__hip_bfloat16*)take((size_t)CH * MIDC * 2);
  float* scfg = (float*)take(1024 * 4);
  float* shfg = (float*)take(1024 * 4);
  float* partials = (float*)take((size_t)BN_ * NCHK * NPIX * 4);               // 5.3 MB
  float* invS     = (float*)take((size_t)BN_ * NPIX * 4);

  prep_scales<<<dim3(4), dim3(256), 0, stream>>>(bf_, gf, betaf, mf, vf,
                                                 bg_, gg, betag, mg, vg, scfg, shfg);
  cvt4<<<dim3(512, 4), dim3(256), 0, stream>>>(Wf, Wg, Wh, Wv,
                                               Wfgb, Wfgb + 512 * 1024, Whb, Wvb);
  transpose_cvt<<<dim3(36, 16, BN_), dim3(256), 0, stream>>>(x, xt);

  // fgT[b][n][r] = sum_c xt[b][n][c] * Wfg[r][c]   (+ fused BN+ReLU per col r)
  gemm_bt<1><<<dim3(18, 8, BN_), dim3(256), 0, stream>>>(
      xt, CH, (long)NPIX * CH, Wfgb, CH, 0L,
      fgT, 1024, (long)NPIX * 1024, CH,
      scfg, shfg, nullptr, 0L, 0.f, nullptr);

  // h[b][m][n] = sum_c Wh[m][c] * xt[b][n][c]  (+ bias per row m)
  gemm_bt<2><<<dim3(4, 18, BN_), dim3(256), 0, stream>>>(
      Whb, CH, 0L, xt, CH, (long)NPIX * CH,
      hbuf, NPIX, (long)MIDC * NPIX, CH,
      bh, nullptr, nullptr, 0L, 0.f, nullptr);

  // E[b][i][j] = exp(z*scale); partial row sums -> partials  (softmax fused)
  const float sc_log2e = (float)(0.044194173824159216 * 1.4426950408889634);
  gemm_bt<6><<<dim3(18, 18, BN_), dim3(256), 0, stream>>>(
      fgT, 1024, (long)NPIX * 1024, fgT + 512, 1024, (long)NPIX * 1024,
      zat, NPIX, (long)NPIX * NPIX, MIDC,
      nullptr, nullptr, nullptr, 0L, sc_log2e, partials);

  reduce_invs<<<dim3(NPIX / 256, BN_), dim3(256), 0, stream>>>(partials, invS);

  // omU[b][i][o] = sum_j E[i][j] * h[o][j]   (unnormalized; EPI0 = r2 binary)
  gemm_bt<0><<<dim3(18, 4, BN_), dim3(256), 0, stream>>>(
      zat, NPIX, (long)NPIX * NPIX, hbuf, NPIX, (long)MIDC * NPIX,
      om, MIDC, (long)NPIX * MIDC, NPIX,
      nullptr, nullptr, nullptr, 0L, 0.f, nullptr);

  // out[b][c][n] = invS[n] * (sum_o Wv[c][o] * omU[b][n][o]) + bv[c] + x[b][c][n]
  gemm_bt<4><<<dim3(8, 18, BN_), dim3(256), 0, stream>>>(
      Wvb, MIDC, 0L, om, MIDC, (long)NPIX * MIDC,
      out, NPIX, (long)CH * NPIX, MIDC,
      bv, invS, x, (long)CH * NPIX, 0.f, nullptr);
}

// Round 8
// 557.666 us; speedup vs baseline: 1.2224x; 1.0163x over previous
//
#include <hip/hip_runtime.h>
#include <hip/hip_bf16.h>

#define BN_  16
#define CH   1024
#define MIDC 512
#define NPIX 2304   // 48*48
#define NCHK 18     // NPIX/128 column chunks per attn row (z partial sums)

typedef __bf16 bf16x8 __attribute__((ext_vector_type(8)));
typedef __bf16 bf16x4 __attribute__((ext_vector_type(4)));
typedef float  f32x4  __attribute__((ext_vector_type(4)));

typedef __attribute__((address_space(1))) void void_g;
typedef __attribute__((address_space(3))) void void_l;

__device__ __forceinline__ void gll16(const void* g, void* l) {
  __builtin_amdgcn_global_load_lds((const void_g*)g, (void_l*)l, 16, 0, 0);
}

// Bare v_exp_f32 (2^x). Safe here: |x| <= ~30, no denormal/range handling needed.
// exp2f would lower to __ocml_exp2_f32 (~20 instrs) — measured +25us on the z GEMM.
__device__ __forceinline__ float fast_exp2(float x) {
  float r;
  asm("v_exp_f32 %0, %1" : "=v"(r) : "v"(x));
  return r;
}

// ---------------------------------------------------------------------------
// 128x128 BT GEMM (r2-measured: 0 bank conflicts, ~5 blocks/CU).
// C[m][n] = sum_k A[m][k]*B[n][k]; BK=64; 256 thr, 2x2 waves, 64x64/wave.
// Chunk-XOR swizzle via pre-swizzled global source; XCD-swizzled grid.
// EPI: 0 none(bf16)
//      1 per-col scale/shift + relu (bf16)
//      2 per-row bias (bf16)
//      4 acc*invS[col] + per-row bias + residual, f32 out      [final conv]
//      6 E=exp2(acc*fscale): LDS-staged coalesced bf16 write + per-(row,
//        128-col-chunk) partial sums -> pw                     [z softmax-fused]
// ---------------------------------------------------------------------------
template<int EPI>
__global__ __launch_bounds__(256)
void gemm_bt(const __hip_bfloat16* __restrict__ Ag, int lda, long sA,
             const __hip_bfloat16* __restrict__ Bg, int ldb, long sB,
             void* __restrict__ Cg, int ldc, long sC,
             int K,
             const float* __restrict__ e0, const float* __restrict__ e1,
             const float* __restrict__ resid, long sR, float fscale,
             float* __restrict__ pw)
{
  __shared__ __align__(16) __hip_bfloat16 lsm[2][128 * 64];   // lA | lB (union: EPI6 C-tile)
  __hip_bfloat16* lA = lsm[0];
  __hip_bfloat16* lB = lsm[1];
  const int tid  = threadIdx.x;
  const int lane = tid & 63;
  const int wave = tid >> 6;

  const int gx = gridDim.x, gy = gridDim.y;
  const int nwg = gx * gy * gridDim.z;
  const int L  = blockIdx.x + gx * (blockIdx.y + gy * blockIdx.z);
  const int wg = (L & 7) * (nwg >> 3) + (L >> 3);
  const int pb = gx * gy;
  const int bz = wg / pb;
  const int rem = wg - bz * pb;
  const int m0 = (rem % gx) * 128;
  const int n0 = (rem / gx) * 128;

  const int srow = tid >> 3;                     // 0..31 (+32 per call)
  const int schk = (tid & 7) ^ (srow & 7);       // pre-swizzled source chunk
  const __hip_bfloat16* Ab = Ag + (long)bz * sA + (long)(m0 + srow) * lda + schk * 8;
  const __hip_bfloat16* Bb = Bg + (long)bz * sB + (long)(n0 + srow) * ldb + schk * 8;
  __hip_bfloat16* lAw = lA + wave * 512;
  __hip_bfloat16* lBw = lB + wave * 512;

  const int wr = wave >> 1, wc = wave & 1;
  const int fr = lane & 15;
  const int fc = lane >> 4;

  f32x4 acc[4][4] = {};

  for (int k0 = 0; k0 < K; k0 += 64) {
#pragma unroll
    for (int c = 0; c < 4; ++c) {
      gll16(Ab + k0 + (long)c * 32 * lda, lAw + c * 2048);
      gll16(Bb + k0 + (long)c * 32 * ldb, lBw + c * 2048);
    }
    __syncthreads();
#pragma unroll
    for (int kk = 0; kk < 2; ++kk) {
      bf16x8 af[4], bfv[4];
#pragma unroll
      for (int i = 0; i < 4; ++i) {
        const int ra = wr * 64 + i * 16 + fr;
        af[i]  = *(const bf16x8*)(lA + ra * 64 + (((kk * 4 + fc) ^ (fr & 7)) * 8));
        const int rb = wc * 64 + i * 16 + fr;
        bfv[i] = *(const bf16x8*)(lB + rb * 64 + (((kk * 4 + fc) ^ (fr & 7)) * 8));
      }
#pragma unroll
      for (int mi = 0; mi < 4; ++mi)
#pragma unroll
        for (int ni = 0; ni < 4; ++ni)
          acc[mi][ni] = __builtin_amdgcn_mfma_f32_16x16x32_bf16(af[mi], bfv[ni], acc[mi][ni], 0, 0, 0);
    }
    __syncthreads();
  }

  // C/D layout: col = lane&15, row = (lane>>4)*4 + reg
  const int rbase = m0 + wr * 64 + (lane >> 4) * 4;
  const int cbase = n0 + wc * 64 + fr;
  if constexpr (EPI == 4) {
    float* Cb = (float*)Cg + (long)bz * sC;
    const float* Rb = resid + (long)bz * sR;
    float ivc[4];
#pragma unroll
    for (int ni = 0; ni < 4; ++ni) ivc[ni] = e1[(long)bz * NPIX + cbase + ni * 16];
#pragma unroll
    for (int mi = 0; mi < 4; ++mi) {
#pragma unroll
      for (int r = 0; r < 4; ++r) {
        const int row = rbase + mi * 16 + r;
        const float bias = e0[row];
#pragma unroll
        for (int ni = 0; ni < 4; ++ni) {
          const long idx = (long)row * ldc + cbase + ni * 16;
          Cb[idx] = acc[mi][ni][r] * ivc[ni] + bias + Rb[idx];
        }
      }
    }
  } else if constexpr (EPI == 6) {
    // Stage E-tile (128x128 bf16 = 32KB) in LDS, then coalesced bf16x8 writes;
    // row partial sums computed in the read-back pass (16 lanes share a row).
    __hip_bfloat16* ct = &lsm[0][0];
    const int rl0 = wr * 64 + (lane >> 4) * 4;
    const int cl0 = wc * 64 + fr;
#pragma unroll
    for (int mi = 0; mi < 4; ++mi) {
#pragma unroll
      for (int r = 0; r < 4; ++r) {
        const int rl = rl0 + mi * 16 + r;
#pragma unroll
        for (int ni = 0; ni < 4; ++ni)
          ct[rl * 128 + cl0 + ni * 16] =
              __float2bfloat16(fast_exp2(acc[mi][ni][r] * fscale));
      }
    }
    __syncthreads();
    __hip_bfloat16* Cb = (__hip_bfloat16*)Cg + (long)bz * sC;
    float* pp = pw + ((long)bz * NCHK + (n0 >> 7)) * NPIX;
#pragma unroll
    for (int i = 0; i < 8; ++i) {
      const int rl = (tid >> 4) + 16 * i;
      const int c8 = (tid & 15) * 8;
      bf16x8 v = *(const bf16x8*)(ct + rl * 128 + c8);
      float s = 0.f;
#pragma unroll
      for (int e = 0; e < 8; ++e) s += (float)v[e];
#pragma unroll
      for (int o = 1; o < 16; o <<= 1) s += __shfl_xor(s, o);
      *(bf16x8*)(Cb + (long)(m0 + rl) * ldc + n0 + c8) = v;
      if ((tid & 15) == 0) pp[m0 + rl] = s;
    }
  } else {
    __hip_bfloat16* Cb = (__hip_bfloat16*)Cg + (long)bz * sC;
#pragma unroll
    for (int mi = 0; mi < 4; ++mi) {
#pragma unroll
      for (int r = 0; r < 4; ++r) {
        const int row = rbase + mi * 16 + r;
#pragma unroll
        for (int ni = 0; ni < 4; ++ni) {
          const int col = cbase + ni * 16;
          float v = acc[mi][ni][r];
          if constexpr (EPI == 1) { v = fmaxf(v * e0[col] + e1[col], 0.f); }
          if constexpr (EPI == 2) { v += e0[row]; }
          Cb[(long)row * ldc + col] = __float2bfloat16(v);
        }
      }
    }
  }
}

// ---------------------------------------------------------------------------
// invS[b][row] = 1 / sum_c partials[b][c][row]   (grid (NPIX/256, BN_))
// ---------------------------------------------------------------------------
__global__ __launch_bounds__(256)
void reduce_invs(const float* __restrict__ pp, float* __restrict__ invS)
{
  const int row = blockIdx.x * 256 + threadIdx.x;
  const int b   = blockIdx.y;
  const float* p = pp + (long)b * NCHK * NPIX;
  float s = 0.f;
#pragma unroll
  for (int c = 0; c < NCHK; ++c) s += p[(long)c * NPIX + row];
  invS[(long)b * NPIX + row] = 1.f / s;
}

// ---------------------------------------------------------------------------
// x[b][c][n] f32  ->  xt[b][n][c] bf16   (64x64 LDS tile transpose)
// ---------------------------------------------------------------------------
__global__ __launch_bounds__(256)
void transpose_cvt(const float* __restrict__ x, __hip_bfloat16* __restrict__ xt)
{
  __shared__ float tile[64 * 65];
  const int n0 = blockIdx.x * 64, c0 = blockIdx.y * 64;
  const long bo = (long)blockIdx.z * CH * NPIX;
  const int t = threadIdx.x;
#pragma unroll
  for (int i = 0; i < 16; ++i) {
    const int idx = i * 256 + t;
    const int cl = idx >> 6, nl = idx & 63;
    tile[cl * 65 + nl] = x[bo + (long)(c0 + cl) * NPIX + n0 + nl];
  }
  __syncthreads();
#pragma unroll
  for (int i = 0; i < 16; ++i) {
    const int idx = i * 256 + t;
    const int nl = idx >> 6, cl = idx & 63;
    xt[bo + (long)(n0 + nl) * CH + c0 + cl] = __float2bfloat16(tile[cl * 65 + nl]);
  }
}

// All four weights are 512*1024 = 524288 elems; one launch, float4 -> bf16x4.
__global__ __launch_bounds__(256)
void cvt4(const float* __restrict__ a, const float* __restrict__ b,
          const float* __restrict__ c, const float* __restrict__ d,
          __hip_bfloat16* oa, __hip_bfloat16* ob,
          __hip_bfloat16* oc, __hip_bfloat16* od)
{
  const int i = (blockIdx.x * 256 + threadIdx.x) * 4;
  const float* s; __hip_bfloat16* o;
  switch (blockIdx.y) {
    case 0:  s = a; o = oa; break;
    case 1:  s = b; o = ob; break;
    case 2:  s = c; o = oc; break;
    default: s = d; o = od; break;
  }
  const float4 v = *(const float4*)(s + i);
  bf16x4 wv;
  wv[0] = (__bf16)v.x; wv[1] = (__bf16)v.y; wv[2] = (__bf16)v.z; wv[3] = (__bf16)v.w;
  *(bf16x4*)(o + i) = wv;
}

// Fold conv-bias + BN into per-channel scale/shift:  out = relu(acc*sc + sh)
__global__ void prep_scales(const float* bf_, const float* gf, const float* bef,
                            const float* mf, const float* vf,
                            const float* bg_, const float* gg, const float* beg,
                            const float* mg, const float* vg,
                            float* sc, float* sh)
{
  const int r = blockIdx.x * 256 + threadIdx.x;
  if (r >= 1024) return;
  int j; const float *b, *g, *be, *m, *vv;
  if (r < 512) { b = bf_; g = gf; be = bef; m = mf; vv = vf; j = r; }
  else         { b = bg_; g = gg; be = beg; m = mg; vv = vg; j = r - 512; }
  const float inv = g[j] / sqrtf(vv[j] + 1e-5f);
  sc[r] = inv;
  sh[r] = (b[j] - m[j]) * inv + be[j];
}

extern "C" void kernel_launch(void* const* d_in, const int* in_sizes, int n_in,
                              void* d_out, int out_size, void* d_ws, size_t ws_size,
                              hipStream_t stream)
{
  const float* x     = (const float*)d_in[0];
  const float* Wf    = (const float*)d_in[1];
  const float* bf_   = (const float*)d_in[2];
  const float* gf    = (const float*)d_in[3];
  const float* betaf = (const float*)d_in[4];
  const float* mf    = (const float*)d_in[5];
  const float* vf    = (const float*)d_in[6];
  const float* Wg    = (const float*)d_in[7];
  const float* bg_   = (const float*)d_in[8];
  const float* gg    = (const float*)d_in[9];
  const float* betag = (const float*)d_in[10];
  const float* mg    = (const float*)d_in[11];
  const float* vg    = (const float*)d_in[12];
  const float* Wh    = (const float*)d_in[13];
  const float* bh    = (const float*)d_in[14];
  const float* Wv    = (const float*)d_in[15];
  const float* bv    = (const float*)d_in[16];
  float* out = (float*)d_out;
  (void)in_sizes; (void)n_in; (void)out_size; (void)ws_size;

  char* ws = (char*)d_ws;
  size_t off = 0;
  auto take = [&](size_t bytes) -> char* {
    char* p = ws + off;
    off += (bytes + 255) & ~(size_t)255;
    return p;
  };
  __hip_bfloat16* xt   = (__hip_bfloat16*)take((size_t)BN_ * NPIX * CH * 2);    // 75.5 MB
  __hip_bfloat16* fgT  = (__hip_bfloat16*)take((size_t)BN_ * NPIX * 1024 * 2);  // 75.5 MB
  __hip_bfloat16* hbuf = (__hip_bfloat16*)take((size_t)BN_ * MIDC * NPIX * 2);  // 37.7 MB
  __hip_bfloat16* om   = (__hip_bfloat16*)take((size_t)BN_ * NPIX * MIDC * 2);  // 37.7 MB
  __hip_bfloat16* zat  = (__hip_bfloat16*)take((size_t)BN_ * NPIX * NPIX * 2);  // 169.9 MB
  __hip_bfloat16* Wfgb = (__hip_bfloat16*)take((size_t)1024 * CH * 2);
  __hip_bfloat16* Whb  = (__hip_bfloat16*)take((size_t)MIDC * CH * 2);
  __hip_bfloat16* Wvb  = (__hip_bfloat16*)take((size_t)CH * MIDC * 2);
  float* scfg = (float*)take(1024 * 4);
  float* shfg = (float*)take(1024 * 4);
  float* partials = (float*)take((size_t)BN_ * NCHK * NPIX * 4);               // 2.7 MB
  float* invS     = (float*)take((size_t)BN_ * NPIX * 4);

  prep_scales<<<dim3(4), dim3(256), 0, stream>>>(bf_, gf, betaf, mf, vf,
                                                 bg_, gg, betag, mg, vg, scfg, shfg);
  cvt4<<<dim3(512, 4), dim3(256), 0, stream>>>(Wf, Wg, Wh, Wv,
                                               Wfgb, Wfgb + 512 * 1024, Whb, Wvb);
  transpose_cvt<<<dim3(36, 16, BN_), dim3(256), 0, stream>>>(x, xt);

  // fgT[b][n][r] = sum_c xt[b][n][c] * Wfg[r][c]   (+ fused BN+ReLU per col r)
  gemm_bt<1><<<dim3(18, 8, BN_), dim3(256), 0, stream>>>(
      xt, CH, (long)NPIX * CH, Wfgb, CH, 0L,
      fgT, 1024, (long)NPIX * 1024, CH,
      scfg, shfg, nullptr, 0L, 0.f, nullptr);

  // h[b][m][n] = sum_c Wh[m][c] * xt[b][n][c]  (+ bias per row m)
  gemm_bt<2><<<dim3(4, 18, BN_), dim3(256), 0, stream>>>(
      Whb, CH, 0L, xt, CH, (long)NPIX * CH,
      hbuf, NPIX, (long)MIDC * NPIX, CH,
      bh, nullptr, nullptr, 0L, 0.f, nullptr);

  // E[b][i][j] = exp(z*scale); per-128-chunk row sums -> partials (softmax fused)
  const float sc_log2e = (float)(0.044194173824159216 * 1.4426950408889634);
  gemm_bt<6><<<dim3(18, 18, BN_), dim3(256), 0, stream>>>(
      fgT, 1024, (long)NPIX * 1024, fgT + 512, 1024, (long)NPIX * 1024,
      zat, NPIX, (long)NPIX * NPIX, MIDC,
      nullptr, nullptr, nullptr, 0L, sc_log2e, partials);

  reduce_invs<<<dim3(NPIX / 256, BN_), dim3(256), 0, stream>>>(partials, invS);

  // omU[b][i][o] = sum_j E[i][j] * h[o][j]   (unnormalized; EPI0 = r2 binary)
  gemm_bt<0><<<dim3(18, 4, BN_), dim3(256), 0, stream>>>(
      zat, NPIX, (long)NPIX * NPIX, hbuf, NPIX, (long)MIDC * NPIX,
      om, MIDC, (long)NPIX * MIDC, NPIX,
      nullptr, nullptr, nullptr, 0L, 0.f, nullptr);

  // out[b][c][n] = invS[n] * (sum_o Wv[c][o] * omU[b][n][o]) + bv[c] + x[b][c][n]
  gemm_bt<4><<<dim3(8, 18, BN_), dim3(256), 0, stream>>>(
      Wvb, MIDC, 0L, om, MIDC, (long)NPIX * MIDC,
      out, NPIX, (long)CH * NPIX, MIDC,
      bv, invS, x, (long)CH * NPIX, 0.f, nullptr);
}

// Round 9
// 543.144 us; speedup vs baseline: 1.2551x; 1.0267x over previous
//
#include <hip/hip_runtime.h>
#include <hip/hip_bf16.h>

#define BN_  16
#define CH   1024
#define MIDC 512
#define NPIX 2304   // 48*48
#define NCHK 18     // NPIX/128 column chunks per attn row (z partial sums)

typedef __bf16 bf16x8 __attribute__((ext_vector_type(8)));
typedef __bf16 bf16x4 __attribute__((ext_vector_type(4)));
typedef float  f32x4  __attribute__((ext_vector_type(4)));

typedef __attribute__((address_space(1))) void void_g;
typedef __attribute__((address_space(3))) void void_l;

__device__ __forceinline__ void gll16(const void* g, void* l) {
  __builtin_amdgcn_global_load_lds((const void_g*)g, (void_l*)l, 16, 0, 0);
}

// Bare v_exp_f32 (2^x). Safe here: |x| <= ~30, no range handling needed.
__device__ __forceinline__ float fast_exp2(float x) {
  float r;
  asm("v_exp_f32 %0, %1" : "=v"(r) : "v"(x));
  return r;
}

// ---------------------------------------------------------------------------
// 128x128 BT GEMM. C[m][n] = sum_k A[m][k]*B[n][k]; BK=64; 256 thr, 2x2 waves.
// Chunk-XOR swizzle via pre-swizzled global source; XCD-swizzled grid.
// EPI: 0 none(bf16) / 1 col scale/shift+relu / 2 row bias
//      4 acc*invS[col] + row bias + residual, f32 out           [final conv]
//      6 E=exp2(acc*fscale): LDS-staged (row-XOR-swizzled) coalesced bf16
//        write + per-(row,128-chunk) partial sums -> pw         [z softmax-fused]
// MINW: min waves/SIMD for __launch_bounds__. 4 => register budget 128/thread
//       (unified VGPR+AGPR) -> 4 waves/SIMD; uses streamed B-frags (2 slots).
// ---------------------------------------------------------------------------
template<int EPI, int MINW>
__global__ __launch_bounds__(256, MINW)
void gemm_bt(const __hip_bfloat16* __restrict__ Ag, int lda, long sA,
             const __hip_bfloat16* __restrict__ Bg, int ldb, long sB,
             void* __restrict__ Cg, int ldc, long sC,
             int K,
             const float* __restrict__ e0, const float* __restrict__ e1,
             const float* __restrict__ resid, long sR, float fscale,
             float* __restrict__ pw)
{
  __shared__ __align__(16) __hip_bfloat16 lsm[2][128 * 64];   // lA | lB (union: EPI6 C-tile)
  __hip_bfloat16* lA = lsm[0];
  __hip_bfloat16* lB = lsm[1];
  const int tid  = threadIdx.x;
  const int lane = tid & 63;
  const int wave = tid >> 6;

  const int gx = gridDim.x, gy = gridDim.y;
  const int nwg = gx * gy * gridDim.z;
  const int L  = blockIdx.x + gx * (blockIdx.y + gy * blockIdx.z);
  const int wg = (L & 7) * (nwg >> 3) + (L >> 3);
  const int pb = gx * gy;
  const int bz = wg / pb;
  const int rem = wg - bz * pb;
  const int m0 = (rem % gx) * 128;
  const int n0 = (rem / gx) * 128;

  const int srow = tid >> 3;                     // 0..31 (+32 per call)
  const int schk = (tid & 7) ^ (srow & 7);       // pre-swizzled source chunk
  const __hip_bfloat16* Ab = Ag + (long)bz * sA + (long)(m0 + srow) * lda + schk * 8;
  const __hip_bfloat16* Bb = Bg + (long)bz * sB + (long)(n0 + srow) * ldb + schk * 8;
  __hip_bfloat16* lAw = lA + wave * 512;
  __hip_bfloat16* lBw = lB + wave * 512;

  const int wr = wave >> 1, wc = wave & 1;
  const int fr = lane & 15;
  const int fc = lane >> 4;

  f32x4 acc[4][4] = {};

  for (int k0 = 0; k0 < K; k0 += 64) {
#pragma unroll
    for (int c = 0; c < 4; ++c) {
      gll16(Ab + k0 + (long)c * 32 * lda, lAw + c * 2048);
      gll16(Bb + k0 + (long)c * 32 * ldb, lBw + c * 2048);
    }
    __syncthreads();
#pragma unroll
    for (int kk = 0; kk < 2; ++kk) {
      const int ks = ((kk * 4 + fc) ^ (fr & 7)) * 8;
      bf16x8 af[4];
#pragma unroll
      for (int i = 0; i < 4; ++i)
        af[i] = *(const bf16x8*)(lA + (wr * 64 + i * 16 + fr) * 64 + ks);
      if constexpr (MINW >= 4) {
        // streamed B-frags: 2 live slots (saves ~8 VGPR -> fits 128 budget)
        bf16x8 bcur = *(const bf16x8*)(lB + (wc * 64 + fr) * 64 + ks);
#pragma unroll
        for (int ni = 0; ni < 4; ++ni) {
          bf16x8 bnxt;
          if (ni < 3)
            bnxt = *(const bf16x8*)(lB + (wc * 64 + (ni + 1) * 16 + fr) * 64 + ks);
#pragma unroll
          for (int mi = 0; mi < 4; ++mi)
            acc[mi][ni] = __builtin_amdgcn_mfma_f32_16x16x32_bf16(af[mi], bcur, acc[mi][ni], 0, 0, 0);
          bcur = bnxt;
        }
      } else {
        bf16x8 bfv[4];
#pragma unroll
        for (int i = 0; i < 4; ++i)
          bfv[i] = *(const bf16x8*)(lB + (wc * 64 + i * 16 + fr) * 64 + ks);
#pragma unroll
        for (int mi = 0; mi < 4; ++mi)
#pragma unroll
          for (int ni = 0; ni < 4; ++ni)
            acc[mi][ni] = __builtin_amdgcn_mfma_f32_16x16x32_bf16(af[mi], bfv[ni], acc[mi][ni], 0, 0, 0);
      }
    }
    __syncthreads();
  }

  // C/D layout: col = lane&15, row = (lane>>4)*4 + reg
  const int rbase = m0 + wr * 64 + (lane >> 4) * 4;
  const int cbase = n0 + wc * 64 + fr;
  if constexpr (EPI == 4) {
    float* Cb = (float*)Cg + (long)bz * sC;
    const float* Rb = resid + (long)bz * sR;
    float ivc[4];
#pragma unroll
    for (int ni = 0; ni < 4; ++ni) ivc[ni] = e1[(long)bz * NPIX + cbase + ni * 16];
#pragma unroll
    for (int mi = 0; mi < 4; ++mi) {
#pragma unroll
      for (int r = 0; r < 4; ++r) {
        const int row = rbase + mi * 16 + r;
        const float bias = e0[row];
#pragma unroll
        for (int ni = 0; ni < 4; ++ni) {
          const long idx = (long)row * ldc + cbase + ni * 16;
          Cb[idx] = acc[mi][ni][r] * ivc[ni] + bias + Rb[idx];
        }
      }
    }
  } else if constexpr (EPI == 6) {
    // Stage E-tile in LDS with row-XOR block swizzle (col ^ ((rl>>2)&3)<<4):
    // the 4 lane-row-groups land in 4 distinct 16-col blocks -> 2 lanes/bank
    // (was 8/bank = 2.65e6 conflicts in r8). Readback un-swizzles; sums are
    // permutation-invariant. Then coalesced bf16x8 global writes.
    __hip_bfloat16* ct = &lsm[0][0];
    const int rl0 = wr * 64 + (lane >> 4) * 4;
    const int cl0 = wc * 64 + fr;
#pragma unroll
    for (int mi = 0; mi < 4; ++mi) {
#pragma unroll
      for (int r = 0; r < 4; ++r) {
        const int rl = rl0 + mi * 16 + r;
        const int swz = ((rl >> 2) & 3) << 4;
#pragma unroll
        for (int ni = 0; ni < 4; ++ni)
          ct[rl * 128 + ((cl0 + ni * 16) ^ swz)] =
              __float2bfloat16(fast_exp2(acc[mi][ni][r] * fscale));
      }
    }
    __syncthreads();
    __hip_bfloat16* Cb = (__hip_bfloat16*)Cg + (long)bz * sC;
    float* pp = pw + ((long)bz * NCHK + (n0 >> 7)) * NPIX;
#pragma unroll
    for (int i = 0; i < 8; ++i) {
      const int rl = (tid >> 4) + 16 * i;
      const int c8 = (tid & 15) * 8;
      bf16x8 v = *(const bf16x8*)(ct + rl * 128 + (c8 ^ (((rl >> 2) & 3) << 4)));
      float s = 0.f;
#pragma unroll
      for (int e = 0; e < 8; ++e) s += (float)v[e];
#pragma unroll
      for (int o = 1; o < 16; o <<= 1) s += __shfl_xor(s, o);
      *(bf16x8*)(Cb + (long)(m0 + rl) * ldc + n0 + c8) = v;
      if ((tid & 15) == 0) pp[m0 + rl] = s;
    }
  } else {
    __hip_bfloat16* Cb = (__hip_bfloat16*)Cg + (long)bz * sC;
#pragma unroll
    for (int mi = 0; mi < 4; ++mi) {
#pragma unroll
      for (int r = 0; r < 4; ++r) {
        const int row = rbase + mi * 16 + r;
#pragma unroll
        for (int ni = 0; ni < 4; ++ni) {
          const int col = cbase + ni * 16;
          float v = acc[mi][ni][r];
          if constexpr (EPI == 1) { v = fmaxf(v * e0[col] + e1[col], 0.f); }
          if constexpr (EPI == 2) { v += e0[row]; }
          Cb[(long)row * ldc + col] = __float2bfloat16(v);
        }
      }
    }
  }
}

// ---------------------------------------------------------------------------
// invS[b][row] = 1 / sum_c partials[b][c][row]   (grid (NPIX/256, BN_))
// ---------------------------------------------------------------------------
__global__ __launch_bounds__(256)
void reduce_invs(const float* __restrict__ pp, float* __restrict__ invS)
{
  const int row = blockIdx.x * 256 + threadIdx.x;
  const int b   = blockIdx.y;
  const float* p = pp + (long)b * NCHK * NPIX;
  float s = 0.f;
#pragma unroll
  for (int c = 0; c < NCHK; ++c) s += p[(long)c * NPIX + row];
  invS[(long)b * NPIX + row] = 1.f / s;
}

// ---------------------------------------------------------------------------
// x[b][c][n] f32  ->  xt[b][n][c] bf16   (64x64 LDS tile transpose)
// ---------------------------------------------------------------------------
__global__ __launch_bounds__(256)
void transpose_cvt(const float* __restrict__ x, __hip_bfloat16* __restrict__ xt)
{
  __shared__ float tile[64 * 65];
  const int n0 = blockIdx.x * 64, c0 = blockIdx.y * 64;
  const long bo = (long)blockIdx.z * CH * NPIX;
  const int t = threadIdx.x;
#pragma unroll
  for (int i = 0; i < 16; ++i) {
    const int idx = i * 256 + t;
    const int cl = idx >> 6, nl = idx & 63;
    tile[cl * 65 + nl] = x[bo + (long)(c0 + cl) * NPIX + n0 + nl];
  }
  __syncthreads();
#pragma unroll
  for (int i = 0; i < 16; ++i) {
    const int idx = i * 256 + t;
    const int nl = idx >> 6, cl = idx & 63;
    xt[bo + (long)(n0 + nl) * CH + c0 + cl] = __float2bfloat16(tile[cl * 65 + nl]);
  }
}

// All four weights are 512*1024 = 524288 elems; one launch, float4 -> bf16x4.
__global__ __launch_bounds__(256)
void cvt4(const float* __restrict__ a, const float* __restrict__ b,
          const float* __restrict__ c, const float* __restrict__ d,
          __hip_bfloat16* oa, __hip_bfloat16* ob,
          __hip_bfloat16* oc, __hip_bfloat16* od)
{
  const int i = (blockIdx.x * 256 + threadIdx.x) * 4;
  const float* s; __hip_bfloat16* o;
  switch (blockIdx.y) {
    case 0:  s = a; o = oa; break;
    case 1:  s = b; o = ob; break;
    case 2:  s = c; o = oc; break;
    default: s = d; o = od; break;
  }
  const float4 v = *(const float4*)(s + i);
  bf16x4 wv;
  wv[0] = (__bf16)v.x; wv[1] = (__bf16)v.y; wv[2] = (__bf16)v.z; wv[3] = (__bf16)v.w;
  *(bf16x4*)(o + i) = wv;
}

// Fold conv-bias + BN into per-channel scale/shift:  out = relu(acc*sc + sh)
__global__ void prep_scales(const float* bf_, const float* gf, const float* bef,
                            const float* mf, const float* vf,
                            const float* bg_, const float* gg, const float* beg,
                            const float* mg, const float* vg,
                            float* sc, float* sh)
{
  const int r = blockIdx.x * 256 + threadIdx.x;
  if (r >= 1024) return;
  int j; const float *b, *g, *be, *m, *vv;
  if (r < 512) { b = bf_; g = gf; be = bef; m = mf; vv = vf; j = r; }
  else         { b = bg_; g = gg; be = beg; m = mg; vv = vg; j = r - 512; }
  const float inv = g[j] / sqrtf(vv[j] + 1e-5f);
  sc[r] = inv;
  sh[r] = (b[j] - m[j]) * inv + be[j];
}

extern "C" void kernel_launch(void* const* d_in, const int* in_sizes, int n_in,
                              void* d_out, int out_size, void* d_ws, size_t ws_size,
                              hipStream_t stream)
{
  const float* x     = (const float*)d_in[0];
  const float* Wf    = (const float*)d_in[1];
  const float* bf_   = (const float*)d_in[2];
  const float* gf    = (const float*)d_in[3];
  const float* betaf = (const float*)d_in[4];
  const float* mf    = (const float*)d_in[5];
  const float* vf    = (const float*)d_in[6];
  const float* Wg    = (const float*)d_in[7];
  const float* bg_   = (const float*)d_in[8];
  const float* gg    = (const float*)d_in[9];
  const float* betag = (const float*)d_in[10];
  const float* mg    = (const float*)d_in[11];
  const float* vg    = (const float*)d_in[12];
  const float* Wh    = (const float*)d_in[13];
  const float* bh    = (const float*)d_in[14];
  const float* Wv    = (const float*)d_in[15];
  const float* bv    = (const float*)d_in[16];
  float* out = (float*)d_out;
  (void)in_sizes; (void)n_in; (void)out_size; (void)ws_size;

  char* ws = (char*)d_ws;
  size_t off = 0;
  auto take = [&](size_t bytes) -> char* {
    char* p = ws + off;
    off += (bytes + 255) & ~(size_t)255;
    return p;
  };
  __hip_bfloat16* xt   = (__hip_bfloat16*)take((size_t)BN_ * NPIX * CH * 2);    // 75.5 MB
  __hip_bfloat16* fgT  = (__hip_bfloat16*)take((size_t)BN_ * NPIX * 1024 * 2);  // 75.5 MB
  __hip_bfloat16* hbuf = (__hip_bfloat16*)take((size_t)BN_ * MIDC * NPIX * 2);  // 37.7 MB
  __hip_bfloat16* om   = (__hip_bfloat16*)take((size_t)BN_ * NPIX * MIDC * 2);  // 37.7 MB
  __hip_bfloat16* zat  = (__hip_bfloat16*)take((size_t)BN_ * NPIX * NPIX * 2);  // 169.9 MB
  __hip_bfloat16* Wfgb = (__hip_bfloat16*)take((size_t)1024 * CH * 2);
  __hip_bfloat16* Whb  = (__hip_bfloat16*)take((size_t)MIDC * CH * 2);
  __hip_bfloat16* Wvb  = (__hip_bfloat16*)take((size_t)CH * MIDC * 2);
  float* scfg = (float*)take(1024 * 4);
  float* shfg = (float*)take(1024 * 4);
  float* partials = (float*)take((size_t)BN_ * NCHK * NPIX * 4);               // 2.7 MB
  float* invS     = (float*)take((size_t)BN_ * NPIX * 4);

  prep_scales<<<dim3(4), dim3(256), 0, stream>>>(bf_, gf, betaf, mf, vf,
                                                 bg_, gg, betag, mg, vg, scfg, shfg);
  cvt4<<<dim3(512, 4), dim3(256), 0, stream>>>(Wf, Wg, Wh, Wv,
                                               Wfgb, Wfgb + 512 * 1024, Whb, Wvb);
  transpose_cvt<<<dim3(36, 16, BN_), dim3(256), 0, stream>>>(x, xt);

  // fgT[b][n][r] = sum_c xt[b][n][c] * Wfg[r][c]   (+ fused BN+ReLU per col r)
  gemm_bt<1, 1><<<dim3(18, 8, BN_), dim3(256), 0, stream>>>(
      xt, CH, (long)NPIX * CH, Wfgb, CH, 0L,
      fgT, 1024, (long)NPIX * 1024, CH,
      scfg, shfg, nullptr, 0L, 0.f, nullptr);

  // h[b][m][n] = sum_c Wh[m][c] * xt[b][n][c]  (+ bias per row m)
  gemm_bt<2, 1><<<dim3(4, 18, BN_), dim3(256), 0, stream>>>(
      Whb, CH, 0L, xt, CH, (long)NPIX * CH,
      hbuf, NPIX, (long)MIDC * NPIX, CH,
      bh, nullptr, nullptr, 0L, 0.f, nullptr);

  // E[b][i][j] = exp(z*scale); per-128-chunk row sums -> partials (softmax fused)
  // MINW=4: 128-reg budget occupancy experiment (A/B control: PV stays MINW=1)
  const float sc_log2e = (float)(0.044194173824159216 * 1.4426950408889634);
  gemm_bt<6, 4><<<dim3(18, 18, BN_), dim3(256), 0, stream>>>(
      fgT, 1024, (long)NPIX * 1024, fgT + 512, 1024, (long)NPIX * 1024,
      zat, NPIX, (long)NPIX * NPIX, MIDC,
      nullptr, nullptr, nullptr, 0L, sc_log2e, partials);

  reduce_invs<<<dim3(NPIX / 256, BN_), dim3(256), 0, stream>>>(partials, invS);

  // omU[b][i][o] = sum_j E[i][j] * h[o][j]   (unnormalized)
  gemm_bt<0, 1><<<dim3(18, 4, BN_), dim3(256), 0, stream>>>(
      zat, NPIX, (long)NPIX * NPIX, hbuf, NPIX, (long)MIDC * NPIX,
      om, MIDC, (long)NPIX * MIDC, NPIX,
      nullptr, nullptr, nullptr, 0L, 0.f, nullptr);

  // out[b][c][n] = invS[n] * (sum_o Wv[c][o] * omU[b][n][o]) + bv[c] + x[b][c][n]
  gemm_bt<4, 1><<<dim3(8, 18, BN_), dim3(256), 0, stream>>>(
      Wvb, MIDC, 0L, om, MIDC, (long)NPIX * MIDC,
      out, NPIX, (long)CH * NPIX, MIDC,
      bv, invS, x, (long)CH * NPIX, 0.f, nullptr);
}

// Round 12
// 492.977 us; speedup vs baseline: 1.3829x; 1.1018x over previous
//
#include <hip/hip_runtime.h>
#include <hip/hip_bf16.h>

#define BN_  16
#define CH   1024
#define MIDC 512
#define NPIX 2304   // 48*48
#define NCHK 18     // NPIX/128 column chunks per attn row (z partial sums)

typedef __bf16 bf16x8 __attribute__((ext_vector_type(8)));
typedef __bf16 bf16x4 __attribute__((ext_vector_type(4)));
typedef float  f32x4  __attribute__((ext_vector_type(4)));

typedef __attribute__((address_space(1))) void void_g;
typedef __attribute__((address_space(3))) void void_l;

__device__ __forceinline__ void gll16(const void* g, void* l) {
  __builtin_amdgcn_global_load_lds((const void_g*)g, (void_l*)l, 16, 0, 0);
}

// Bare v_exp_f32 (2^x). Safe here: |x| <= ~30, no range handling needed.
__device__ __forceinline__ float fast_exp2(float x) {
  float r;
  asm("v_exp_f32 %0, %1" : "=v"(r) : "v"(x));
  return r;
}

// ---------------------------------------------------------------------------
// 128x128 BT GEMM. C[m][n] = sum_k A[m][k]*B[n][k]; BK=64; 256 thr, 2x2 waves.
// Chunk-XOR swizzle via pre-swizzled global source; XCD-swizzled grid.
// __launch_bounds__(256,4): 128-reg budget (unified VGPR+AGPR) -> 4 waves/SIMD
// (r9 A/B on z: +occupancy beat the 3-wave MINW=1 build). B-frags streamed
// (2 live slots) to fit the budget.
// EPI: 0 none(bf16) / 1 col scale/shift+relu / 2 row bias
//      4 acc*invS[col] + row bias + residual, f32 out           [final conv]
//      6 E=exp2(acc*fscale): LDS-staged (row-XOR-swizzled) coalesced bf16
//        write + per-(row,128-chunk) partial sums -> pw         [z softmax-fused]
// ---------------------------------------------------------------------------
template<int EPI>
__global__ __launch_bounds__(256, 4)
void gemm_bt(const __hip_bfloat16* __restrict__ Ag, int lda, long sA,
             const __hip_bfloat16* __restrict__ Bg, int ldb, long sB,
             void* __restrict__ Cg, int ldc, long sC,
             int K,
             const float* __restrict__ e0, const float* __restrict__ e1,
             const float* __restrict__ resid, long sR, float fscale,
             float* __restrict__ pw)
{
  __shared__ __align__(16) __hip_bfloat16 lsm[2][128 * 64];   // lA | lB (union: EPI6 C-tile)
  __hip_bfloat16* lA = lsm[0];
  __hip_bfloat16* lB = lsm[1];
  const int tid  = threadIdx.x;
  const int lane = tid & 63;
  const int wave = tid >> 6;

  const int gx = gridDim.x, gy = gridDim.y;
  const int nwg = gx * gy * gridDim.z;
  const int L  = blockIdx.x + gx * (blockIdx.y + gy * blockIdx.z);
  const int wg = (L & 7) * (nwg >> 3) + (L >> 3);
  const int pb = gx * gy;
  const int bz = wg / pb;
  const int rem = wg - bz * pb;
  const int m0 = (rem % gx) * 128;
  const int n0 = (rem / gx) * 128;

  const int srow = tid >> 3;                     // 0..31 (+32 per call)
  const int schk = (tid & 7) ^ (srow & 7);       // pre-swizzled source chunk
  const __hip_bfloat16* Ab = Ag + (long)bz * sA + (long)(m0 + srow) * lda + schk * 8;
  const __hip_bfloat16* Bb = Bg + (long)bz * sB + (long)(n0 + srow) * ldb + schk * 8;
  __hip_bfloat16* lAw = lA + wave * 512;
  __hip_bfloat16* lBw = lB + wave * 512;

  const int wr = wave >> 1, wc = wave & 1;
  const int fr = lane & 15;
  const int fc = lane >> 4;

  f32x4 acc[4][4] = {};

  for (int k0 = 0; k0 < K; k0 += 64) {
#pragma unroll
    for (int c = 0; c < 4; ++c) {
      gll16(Ab + k0 + (long)c * 32 * lda, lAw + c * 2048);
      gll16(Bb + k0 + (long)c * 32 * ldb, lBw + c * 2048);
    }
    __syncthreads();
#pragma unroll
    for (int kk = 0; kk < 2; ++kk) {
      const int ks = ((kk * 4 + fc) ^ (fr & 7)) * 8;
      bf16x8 af[4];
#pragma unroll
      for (int i = 0; i < 4; ++i)
        af[i] = *(const bf16x8*)(lA + (wr * 64 + i * 16 + fr) * 64 + ks);
      // streamed B-frags: 2 live slots (fits the 128-reg budget)
      bf16x8 bcur = *(const bf16x8*)(lB + (wc * 64 + fr) * 64 + ks);
#pragma unroll
      for (int ni = 0; ni < 4; ++ni) {
        bf16x8 bnxt;
        if (ni < 3)
          bnxt = *(const bf16x8*)(lB + (wc * 64 + (ni + 1) * 16 + fr) * 64 + ks);
#pragma unroll
        for (int mi = 0; mi < 4; ++mi)
          acc[mi][ni] = __builtin_amdgcn_mfma_f32_16x16x32_bf16(af[mi], bcur, acc[mi][ni], 0, 0, 0);
        bcur = bnxt;
      }
    }
    __syncthreads();
  }

  // C/D layout: col = lane&15, row = (lane>>4)*4 + reg
  const int rbase = m0 + wr * 64 + (lane >> 4) * 4;
  const int cbase = n0 + wc * 64 + fr;
  if constexpr (EPI == 4) {
    float* Cb = (float*)Cg + (long)bz * sC;
    const float* Rb = resid + (long)bz * sR;
    float ivc[4];
#pragma unroll
    for (int ni = 0; ni < 4; ++ni) ivc[ni] = e1[(long)bz * NPIX + cbase + ni * 16];
#pragma unroll
    for (int mi = 0; mi < 4; ++mi) {
#pragma unroll
      for (int r = 0; r < 4; ++r) {
        const int row = rbase + mi * 16 + r;
        const float bias = e0[row];
#pragma unroll
        for (int ni = 0; ni < 4; ++ni) {
          const long idx = (long)row * ldc + cbase + ni * 16;
          Cb[idx] = acc[mi][ni][r] * ivc[ni] + bias + Rb[idx];
        }
      }
    }
  } else if constexpr (EPI == 6) {
    // Stage E-tile in LDS with row-XOR block swizzle -> 2 lanes/bank (free),
    // then coalesced bf16x8 global writes + readback row partial sums.
    __hip_bfloat16* ct = &lsm[0][0];
    const int rl0 = wr * 64 + (lane >> 4) * 4;
    const int cl0 = wc * 64 + fr;
#pragma unroll
    for (int mi = 0; mi < 4; ++mi) {
#pragma unroll
      for (int r = 0; r < 4; ++r) {
        const int rl = rl0 + mi * 16 + r;
        const int swz = ((rl >> 2) & 3) << 4;
#pragma unroll
        for (int ni = 0; ni < 4; ++ni)
          ct[rl * 128 + ((cl0 + ni * 16) ^ swz)] =
              __float2bfloat16(fast_exp2(acc[mi][ni][r] * fscale));
      }
    }
    __syncthreads();
    __hip_bfloat16* Cb = (__hip_bfloat16*)Cg + (long)bz * sC;
    float* pp = pw + ((long)bz * NCHK + (n0 >> 7)) * NPIX;
#pragma unroll
    for (int i = 0; i < 8; ++i) {
      const int rl = (tid >> 4) + 16 * i;
      const int c8 = (tid & 15) * 8;
      bf16x8 v = *(const bf16x8*)(ct + rl * 128 + (c8 ^ (((rl >> 2) & 3) << 4)));
      float s = 0.f;
#pragma unroll
      for (int e = 0; e < 8; ++e) s += (float)v[e];
#pragma unroll
      for (int o = 1; o < 16; o <<= 1) s += __shfl_xor(s, o);
      *(bf16x8*)(Cb + (long)(m0 + rl) * ldc + n0 + c8) = v;
      if ((tid & 15) == 0) pp[m0 + rl] = s;
    }
  } else {
    __hip_bfloat16* Cb = (__hip_bfloat16*)Cg + (long)bz * sC;
#pragma unroll
    for (int mi = 0; mi < 4; ++mi) {
#pragma unroll
      for (int r = 0; r < 4; ++r) {
        const int row = rbase + mi * 16 + r;
#pragma unroll
        for (int ni = 0; ni < 4; ++ni) {
          const int col = cbase + ni * 16;
          float v = acc[mi][ni][r];
          if constexpr (EPI == 1) { v = fmaxf(v * e0[col] + e1[col], 0.f); }
          if constexpr (EPI == 2) { v += e0[row]; }
          Cb[(long)row * ldc + col] = __float2bfloat16(v);
        }
      }
    }
  }
}

// ---------------------------------------------------------------------------
// invS[b][row] = 1 / sum_c partials[b][c][row]   (grid (NPIX/256, BN_))
// ---------------------------------------------------------------------------
__global__ __launch_bounds__(256)
void reduce_invs(const float* __restrict__ pp, float* __restrict__ invS)
{
  const int row = blockIdx.x * 256 + threadIdx.x;
  const int b   = blockIdx.y;
  const float* p = pp + (long)b * NCHK * NPIX;
  float s = 0.f;
#pragma unroll
  for (int c = 0; c < NCHK; ++c) s += p[(long)c * NPIX + row];
  invS[(long)b * NPIX + row] = 1.f / s;
}

// ---------------------------------------------------------------------------
// x[b][c][n] f32  ->  xt[b][n][c] bf16   (64x64 LDS tile transpose)
// ---------------------------------------------------------------------------
__global__ __launch_bounds__(256)
void transpose_cvt(const float* __restrict__ x, __hip_bfloat16* __restrict__ xt)
{
  __shared__ float tile[64 * 65];
  const int n0 = blockIdx.x * 64, c0 = blockIdx.y * 64;
  const long bo = (long)blockIdx.z * CH * NPIX;
  const int t = threadIdx.x;
#pragma unroll
  for (int i = 0; i < 16; ++i) {
    const int idx = i * 256 + t;
    const int cl = idx >> 6, nl = idx & 63;
    tile[cl * 65 + nl] = x[bo + (long)(c0 + cl) * NPIX + n0 + nl];
  }
  __syncthreads();
#pragma unroll
  for (int i = 0; i < 16; ++i) {
    const int idx = i * 256 + t;
    const int nl = idx >> 6, cl = idx & 63;
    xt[bo + (long)(n0 + nl) * CH + c0 + cl] = __float2bfloat16(tile[cl * 65 + nl]);
  }
}

// All four weights are 512*1024 = 524288 elems; one launch, float4 -> bf16x4.
__global__ __launch_bounds__(256)
void cvt4(const float* __restrict__ a, const float* __restrict__ b,
          const float* __restrict__ c, const float* __restrict__ d,
          __hip_bfloat16* oa, __hip_bfloat16* ob,
          __hip_bfloat16* oc, __hip_bfloat16* od)
{
  const int i = (blockIdx.x * 256 + threadIdx.x) * 4;
  const float* s; __hip_bfloat16* o;
  switch (blockIdx.y) {
    case 0:  s = a; o = oa; break;
    case 1:  s = b; o = ob; break;
    case 2:  s = c; o = oc; break;
    default: s = d; o = od; break;
  }
  const float4 v = *(const float4*)(s + i);
  bf16x4 wv;
  wv[0] = (__bf16)v.x; wv[1] = (__bf16)v.y; wv[2] = (__bf16)v.z; wv[3] = (__bf16)v.w;
  *(bf16x4*)(o + i) = wv;
}

// Fold conv-bias + BN into per-channel scale/shift:  out = relu(acc*sc + sh)
__global__ void prep_scales(const float* bf_, const float* gf, const float* bef,
                            const float* mf, const float* vf,
                            const float* bg_, const float* gg, const float* beg,
                            const float* mg, const float* vg,
                            float* sc, float* sh)
{
  const int r = blockIdx.x * 256 + threadIdx.x;
  if (r >= 1024) return;
  int j; const float *b, *g, *be, *m, *vv;
  if (r < 512) { b = bf_; g = gf; be = bef; m = mf; vv = vf; j = r; }
  else         { b = bg_; g = gg; be = beg; m = mg; vv = vg; j = r - 512; }
  const float inv = g[j] / sqrtf(vv[j] + 1e-5f);
  sc[r] = inv;
  sh[r] = (b[j] - m[j]) * inv + be[j];
}

extern "C" void kernel_launch(void* const* d_in, const int* in_sizes, int n_in,
                              void* d_out, int out_size, void* d_ws, size_t ws_size,
                              hipStream_t stream)
{
  const float* x     = (const float*)d_in[0];
  const float* Wf    = (const float*)d_in[1];
  const float* bf_   = (const float*)d_in[2];
  const float* gf    = (const float*)d_in[3];
  const float* betaf = (const float*)d_in[4];
  const float* mf    = (const float*)d_in[5];
  const float* vf    = (const float*)d_in[6];
  const float* Wg    = (const float*)d_in[7];
  const float* bg_   = (const float*)d_in[8];
  const float* gg    = (const float*)d_in[9];
  const float* betag = (const float*)d_in[10];
  const float* mg    = (const float*)d_in[11];
  const float* vg    = (const float*)d_in[12];
  const float* Wh    = (const float*)d_in[13];
  const float* bh    = (const float*)d_in[14];
  const float* Wv    = (const float*)d_in[15];
  const float* bv    = (const float*)d_in[16];
  float* out = (float*)d_out;
  (void)in_sizes; (void)n_in; (void)out_size; (void)ws_size;

  char* ws = (char*)d_ws;
  size_t off = 0;
  auto take = [&](size_t bytes) -> char* {
    char* p = ws + off;
    off += (bytes + 255) & ~(size_t)255;
    return p;
  };
  __hip_bfloat16* xt   = (__hip_bfloat16*)take((size_t)BN_ * NPIX * CH * 2);    // 75.5 MB
  __hip_bfloat16* fgT  = (__hip_bfloat16*)take((size_t)BN_ * NPIX * 1024 * 2);  // 75.5 MB
  __hip_bfloat16* hbuf = (__hip_bfloat16*)take((size_t)BN_ * MIDC * NPIX * 2);  // 37.7 MB
  __hip_bfloat16* om   = (__hip_bfloat16*)take((size_t)BN_ * NPIX * MIDC * 2);  // 37.7 MB
  __hip_bfloat16* zat  = (__hip_bfloat16*)take((size_t)BN_ * NPIX * NPIX * 2);  // 169.9 MB
  __hip_bfloat16* Wfgb = (__hip_bfloat16*)take((size_t)1024 * CH * 2);
  __hip_bfloat16* Whb  = (__hip_bfloat16*)take((size_t)MIDC * CH * 2);
  __hip_bfloat16* Wvb  = (__hip_bfloat16*)take((size_t)CH * MIDC * 2);
  float* scfg = (float*)take(1024 * 4);
  float* shfg = (float*)take(1024 * 4);
  float* partials = (float*)take((size_t)BN_ * NCHK * NPIX * 4);               // 2.7 MB
  float* invS     = (float*)take((size_t)BN_ * NPIX * 4);

  prep_scales<<<dim3(4), dim3(256), 0, stream>>>(bf_, gf, betaf, mf, vf,
                                                 bg_, gg, betag, mg, vg, scfg, shfg);
  cvt4<<<dim3(512, 4), dim3(256), 0, stream>>>(Wf, Wg, Wh, Wv,
                                               Wfgb, Wfgb + 512 * 1024, Whb, Wvb);
  transpose_cvt<<<dim3(36, 16, BN_), dim3(256), 0, stream>>>(x, xt);

  // fgT[b][n][r] = sum_c xt[b][n][c] * Wfg[r][c]   (+ fused BN+ReLU per col r)
  gemm_bt<1><<<dim3(18, 8, BN_), dim3(256), 0, stream>>>(
      xt, CH, (long)NPIX * CH, Wfgb, CH, 0L,
      fgT, 1024, (long)NPIX * 1024, CH,
      scfg, shfg, nullptr, 0L, 0.f, nullptr);

  // h[b][m][n] = sum_c Wh[m][c] * xt[b][n][c]  (+ bias per row m)
  gemm_bt<2><<<dim3(4, 18, BN_), dim3(256), 0, stream>>>(
      Whb, CH, 0L, xt, CH, (long)NPIX * CH,
      hbuf, NPIX, (long)MIDC * NPIX, CH,
      bh, nullptr, nullptr, 0L, 0.f, nullptr);

  // E[b][i][j] = exp(z*scale); per-128-chunk row sums -> partials (softmax fused)
  const float sc_log2e = (float)(0.044194173824159216 * 1.4426950408889634);
  gemm_bt<6><<<dim3(18, 18, BN_), dim3(256), 0, stream>>>(
      fgT, 1024, (long)NPIX * 1024, fgT + 512, 1024, (long)NPIX * 1024,
      zat, NPIX, (long)NPIX * NPIX, MIDC,
      nullptr, nullptr, nullptr, 0L, sc_log2e, partials);

  reduce_invs<<<dim3(NPIX / 256, BN_), dim3(256), 0, stream>>>(partials, invS);

  // omU[b][i][o] = sum_j E[i][j] * h[o][j]   (unnormalized)
  gemm_bt<0><<<dim3(18, 4, BN_), dim3(256), 0, stream>>>(
      zat, NPIX, (long)NPIX * NPIX, hbuf, NPIX, (long)MIDC * NPIX,
      om, MIDC, (long)NPIX * MIDC, NPIX,
      nullptr, nullptr, nullptr, 0L, 0.f, nullptr);

  // out[b][c][n] = invS[n] * (sum_o Wv[c][o] * omU[b][n][o]) + bv[c] + x[b][c][n]
  gemm_bt<4><<<dim3(8, 18, BN_), dim3(256), 0, stream>>>(
      Wvb, MIDC, 0L, om, MIDC, (long)NPIX * MIDC,
      out, NPIX, (long)CH * NPIX, MIDC,
      bv, invS, x, (long)CH * NPIX, 0.f, nullptr);
}